// Round 4
// baseline (335.018 us; speedup 1.0000x reference)
//
#include <hip/hip_runtime.h>
#include <cmath>

constexpr int B = 2, L = 4096, D = 256, H = 8, NC = 3;
constexpr int TOP_N = 8, R = 32;
constexpr int LS = 1000, LE = 3000;
constexpr int NL = 2;
constexpr int FF = 4 * D;                        // 1024
constexpr int Q_MAX = 2 * TOP_N * (2 * R + 1);   // 1040
constexpr int HD = D / H;                        // 32
constexpr int QROWS = B * Q_MAX;                 // 2080
constexpr int KVROWS = B * L;                    // 8192
constexpr int NQT = (Q_MAX + 31) / 32;           // 33 q-tiles of 32
constexpr int NREG = LE - LS;                    // 2000
constexpr int NSPLIT = 8;                        // split-K waves per block
constexpr int KCHUNK = L / NSPLIT;               // 512 keys per wave

typedef __attribute__((ext_vector_type(8))) short bf16x8;
typedef __attribute__((ext_vector_type(4))) float f32x4;
typedef __attribute__((ext_vector_type(4))) int i32x4;
typedef unsigned short u16;

union fr {
  bf16x8 h;
  i32x4 i;
};

__device__ __forceinline__ u16 f2bs(float f) {
  unsigned int u = __float_as_uint(f);
  unsigned int r = u + 0x7fffu + ((u >> 16) & 1u);
  return (u16)(r >> 16);
}
__device__ __forceinline__ float bs2f(u16 s) {
  return __uint_as_float(((unsigned int)s) << 16);
}
__device__ __forceinline__ float gelu_exact(float x) {
  return 0.5f * x * (1.f + erff(x * 0.70710678118654752440f));
}
__device__ __forceinline__ unsigned cvt_pk(float lo, float hi) {
  unsigned r;
  asm("v_cvt_pk_bf16_f32 %0, %1, %2" : "=v"(r) : "v"(lo), "v"(hi));
  return r;
}

// ---------------------------------------------------------------------------
// Vicinity selection. One 1024-thread block per batch.
// ---------------------------------------------------------------------------
__global__ __launch_bounds__(1024) void select_kernel(
    const float* __restrict__ logits, int* __restrict__ idx_out,
    int* __restrict__ mask_out) {
  int b = blockIdx.x;
  int tid = threadIdx.x;
  __shared__ float vv[2][NREG];
  __shared__ int centers[2 * TOP_N];
  __shared__ unsigned present[L / 32];
  __shared__ float wred[16];
  __shared__ int wredi[16];
  __shared__ int offs[128];
  __shared__ int wtot[2];

  for (int p = tid; p < NREG; p += 1024) {
    const float* lg = logits + ((long)b * L + LS + p) * NC;
    float x0 = lg[0], x1 = lg[1], x2 = lg[2];
    float m = fmaxf(x0, fmaxf(x1, x2));
    float lse = m + logf(expf(x0 - m) + expf(x1 - m) + expf(x2 - m));
    vv[0][p] = x2 - lse;  // don
    vv[1][p] = x1 - lse;  // acc
  }
  if (tid < 128) present[tid] = 0;
  __syncthreads();

  for (int sel = 0; sel < 2; ++sel) {
    for (int t = 0; t < TOP_N; ++t) {
      float bv = -INFINITY;
      int bi = 0x7fffffff;
      for (int p = tid; p < NREG; p += 1024) {
        float x = vv[sel][p];
        if (x > bv || (x == bv && p < bi)) { bv = x; bi = p; }
      }
#pragma unroll
      for (int off = 32; off; off >>= 1) {
        float ov = __shfl_xor(bv, off, 64);
        int oi = __shfl_xor(bi, off, 64);
        if (ov > bv || (ov == bv && oi < bi)) { bv = ov; bi = oi; }
      }
      if ((tid & 63) == 0) { wred[tid >> 6] = bv; wredi[tid >> 6] = bi; }
      __syncthreads();
      if (tid < 64) {
        bv = (tid < 16) ? wred[tid] : -INFINITY;
        bi = (tid < 16) ? wredi[tid] : 0x7fffffff;
#pragma unroll
        for (int off = 8; off; off >>= 1) {
          float ov = __shfl_xor(bv, off, 64);
          int oi = __shfl_xor(bi, off, 64);
          if (ov > bv || (ov == bv && oi < bi)) { bv = ov; bi = oi; }
        }
        if (tid == 0) {
          centers[sel * TOP_N + t] = LS + bi;
          vv[sel][bi] = -INFINITY;
        }
      }
      __syncthreads();
    }
  }

  for (int j = tid; j < Q_MAX; j += 1024) {
    int c = centers[j / (2 * R + 1)];
    int off = j % (2 * R + 1) - R;
    int v = c + off;
    v = v < 0 ? 0 : (v > L - 1 ? L - 1 : v);
    atomicOr(&present[v >> 5], 1u << (v & 31));
  }
  __syncthreads();

  int cnt = (tid < 128) ? __popc(present[tid]) : 0;
  if (tid < 128) {
    int x = cnt;
#pragma unroll
    for (int off = 1; off < 64; off <<= 1) {
      int o = __shfl_up(x, off, 64);
      if ((tid & 63) >= off) x += o;
    }
    if ((tid & 63) == 63) wtot[tid >> 6] = x;
    offs[tid] = x - cnt;
  }
  __syncthreads();
  int total = wtot[0] + wtot[1];
  if (tid < 128) {
    int base = offs[tid] + ((tid >= 64) ? wtot[0] : 0);
    unsigned mword = present[tid];
    while (mword) {
      int i = __ffs(mword) - 1;
      mword &= mword - 1;
      idx_out[b * Q_MAX + base] = tid * 32 + i;
      mask_out[b * Q_MAX + base] = 1;
      ++base;
    }
  }
  for (int j = total + tid; j < Q_MAX; j += 1024) {
    idx_out[b * Q_MAX + j] = L;
    mask_out[b * Q_MAX + j] = 0;
  }
}

// ---------------------------------------------------------------------------
__global__ __launch_bounds__(256) void gather_kernel(
    const float* __restrict__ enc, const int* __restrict__ idx,
    float* __restrict__ q_stream) {
  int row = blockIdx.x;
  int b = row / Q_MAX;
  int p = idx[row];
  float v = 0.f;
  if (p < L) v = enc[((long)b * L + p) * D + threadIdx.x];
  q_stream[(long)row * D + threadIdx.x] = v;
}

// ---------------------------------------------------------------------------
// LayerNorm fp32 in -> bf16 out (single gamma/beta)
// ---------------------------------------------------------------------------
__global__ __launch_bounds__(256) void ln_bf16(
    const float* __restrict__ in, u16* __restrict__ out,
    const float* __restrict__ gg, const float* __restrict__ bb) {
  long row = blockIdx.x;
  int tid = threadIdx.x;
  float x = in[row * D + tid];
  float s1 = x, s2 = x * x;
#pragma unroll
  for (int off = 32; off; off >>= 1) {
    s1 += __shfl_xor(s1, off, 64);
    s2 += __shfl_xor(s2, off, 64);
  }
  __shared__ float p1[4], p2[4];
  int w = tid >> 6;
  if ((tid & 63) == 0) { p1[w] = s1; p2[w] = s2; }
  __syncthreads();
  s1 = p1[0] + p1[1] + p1[2] + p1[3];
  s2 = p2[0] + p2[1] + p2[2] + p2[3];
  float mean = s1 * (1.f / D);
  float var = fmaxf(s2 * (1.f / D) - mean * mean, 0.f);
  float r = rsqrtf(var + 1e-5f);
  out[row * D + tid] = f2bs((x - mean) * r * gg[tid] + bb[tid]);
}

// LayerNorm of enc with BOTH layers' gamma/beta -> two bf16 outputs
__global__ __launch_bounds__(256) void ln_kv2(
    const float* __restrict__ in, u16* __restrict__ o0, u16* __restrict__ o1,
    const float* __restrict__ g) {
  long row = blockIdx.x;
  int tid = threadIdx.x;
  float x = in[row * D + tid];
  float s1 = x, s2 = x * x;
#pragma unroll
  for (int off = 32; off; off >>= 1) {
    s1 += __shfl_xor(s1, off, 64);
    s2 += __shfl_xor(s2, off, 64);
  }
  __shared__ float p1[4], p2[4];
  int w = tid >> 6;
  if ((tid & 63) == 0) { p1[w] = s1; p2[w] = s2; }
  __syncthreads();
  s1 = p1[0] + p1[1] + p1[2] + p1[3];
  s2 = p2[0] + p2[1] + p2[2] + p2[3];
  float mean = s1 * (1.f / D);
  float var = fmaxf(s2 * (1.f / D) - mean * mean, 0.f);
  float r = rsqrtf(var + 1e-5f);
  float xn = (x - mean) * r;
  o0[row * D + tid] = f2bs(xn * g[tid] + g[2 * D + tid]);
  o1[row * D + tid] = f2bs(xn * g[D + tid] + g[3 * D + tid]);
}

__global__ __launch_bounds__(256) void pack_lnkv(
    const float* __restrict__ g, const float* __restrict__ bb,
    float* __restrict__ dst) {
  int t = blockIdx.x * 256 + threadIdx.x;
  if (t < 2 * D) dst[t] = g[t];
  else if (t < 4 * D) dst[t] = bb[t - 2 * D];
}

// ---------------------------------------------------------------------------
// Batched weight transpose+bf16: all NL layers, all 6 matrices, one dispatch.
// ---------------------------------------------------------------------------
__global__ __launch_bounds__(256) void transpose_all(
    const float* __restrict__ Wq_, const float* __restrict__ Wk_,
    const float* __restrict__ Wv_, const float* __restrict__ Wo_,
    const float* __restrict__ W1_, const float* __restrict__ W2_,
    u16* __restrict__ WT) {
  const long DD = (long)D * D, DFF = (long)D * FF;
  const long LSTR = 4 * DD + 2 * DFF;
  long t = (long)blockIdx.x * 256 + threadIdx.x;
  if (t >= NL * LSTR) return;
  int l = (int)(t / LSTR);
  long r = t - (long)l * LSTR;
  const float* src;
  long dstbase, e;
  int K_, N_;
  if (r < 4 * DD) {
    int which = (int)(r >> 16);
    e = r & (DD - 1);
    K_ = D; N_ = D;
    src = (which == 0 ? Wk_ : which == 1 ? Wv_ : which == 2 ? Wq_ : Wo_) +
          (long)l * DD;
    dstbase = l * LSTR + which * DD;
  } else if (r < 4 * DD + DFF) {
    e = r - 4 * DD;
    K_ = D; N_ = FF;
    src = W1_ + (long)l * DFF;
    dstbase = l * LSTR + 4 * DD;
  } else {
    e = r - 4 * DD - DFF;
    K_ = FF; N_ = D;
    src = W2_ + (long)l * DFF;
    dstbase = l * LSTR + 4 * DD + DFF;
  }
  int k = (int)(e / N_), n = (int)(e % N_);
  WT[dstbase + (long)n * K_ + k] = f2bs(src[e]);
}

// ---------------------------------------------------------------------------
// bf16 MFMA GEMM (64x64 tile, BK=32, 4 waves). EPI 0: bias->bf16; 1: gelu->
// bf16; 2: resid+mask->f32; 3: bias + per-head transposed bf16 out Vt.
// ---------------------------------------------------------------------------
template <int EPI>
__global__ __launch_bounds__(256) void gemm_mfma(
    const u16* __restrict__ A, const u16* __restrict__ BT,
    const float* __restrict__ bias, void* __restrict__ Cv,
    const float* __restrict__ resid, const int* __restrict__ mask, int M,
    int N, int K) {
  __shared__ short As[64][40];
  __shared__ short Bs[64][40];
  int bm = blockIdx.y * 64, bn = blockIdx.x * 64;
  int tid = threadIdx.x;
  int lane = tid & 63, w = tid >> 6;
  int g = lane >> 4, li = lane & 15;
  int wr = w >> 1, wc = w & 1;
  f32x4 acc[2][2] = {};

  int srow = tid >> 2, skc = (tid & 3) * 8;
  for (int k0 = 0; k0 < K; k0 += 32) {
    {
      int grow = bm + srow;
      bf16x8 av = {};
      if (grow < M)
        av = *reinterpret_cast<const bf16x8*>(A + (long)grow * K + k0 + skc);
      *reinterpret_cast<bf16x8*>(&As[srow][skc]) = av;
      bf16x8 bv = *reinterpret_cast<const bf16x8*>(
          BT + (long)(bn + srow) * K + k0 + skc);
      *reinterpret_cast<bf16x8*>(&Bs[srow][skc]) = bv;
    }
    __syncthreads();
    bf16x8 a0 = *reinterpret_cast<const bf16x8*>(&As[wr * 32 + li][g * 8]);
    bf16x8 a1 = *reinterpret_cast<const bf16x8*>(&As[wr * 32 + 16 + li][g * 8]);
    bf16x8 b0 = *reinterpret_cast<const bf16x8*>(&Bs[wc * 32 + li][g * 8]);
    bf16x8 b1 = *reinterpret_cast<const bf16x8*>(&Bs[wc * 32 + 16 + li][g * 8]);
    acc[0][0] = __builtin_amdgcn_mfma_f32_16x16x32_bf16(a0, b0, acc[0][0], 0, 0, 0);
    acc[0][1] = __builtin_amdgcn_mfma_f32_16x16x32_bf16(a0, b1, acc[0][1], 0, 0, 0);
    acc[1][0] = __builtin_amdgcn_mfma_f32_16x16x32_bf16(a1, b0, acc[1][0], 0, 0, 0);
    acc[1][1] = __builtin_amdgcn_mfma_f32_16x16x32_bf16(a1, b1, acc[1][1], 0, 0, 0);
    __syncthreads();
  }

  if constexpr (EPI == 3) {
    __shared__ u16 Ct[64][72];
#pragma unroll
    for (int mr = 0; mr < 2; ++mr)
#pragma unroll
      for (int nr = 0; nr < 2; ++nr)
#pragma unroll
        for (int r = 0; r < 4; ++r) {
          int rowL = wr * 32 + mr * 16 + g * 4 + r;
          int colL = wc * 32 + nr * 16 + li;
          Ct[colL][rowL] = f2bs(acc[mr][nr][r] + bias[bn + colL]);
        }
    __syncthreads();
    int colL = tid >> 2, rseg = (tid & 3) * 16;
    int gcol = bn + colL;
    int hh = gcol >> 5, dd = gcol & (HD - 1);
    int grow = bm + rseg;
    int bb2 = grow >> 12, key = grow & (L - 1);
    u16* dst = (u16*)Cv + ((long)(bb2 * H + hh) * HD + dd) * L + key;
    *reinterpret_cast<bf16x8*>(dst) =
        *reinterpret_cast<const bf16x8*>(&Ct[colL][rseg]);
    *reinterpret_cast<bf16x8*>(dst + 8) =
        *reinterpret_cast<const bf16x8*>(&Ct[colL][rseg + 8]);
  } else {
#pragma unroll
    for (int mr = 0; mr < 2; ++mr)
#pragma unroll
      for (int nr = 0; nr < 2; ++nr)
#pragma unroll
        for (int r = 0; r < 4; ++r) {
          int row = bm + wr * 32 + mr * 16 + g * 4 + r;
          int col = bn + wc * 32 + nr * 16 + li;
          if (row >= M) continue;
          float v = acc[mr][nr][r] + bias[col];
          if (EPI == 1) v = gelu_exact(v);
          if (EPI == 2) {
            v += resid[(long)row * N + col];
            v = mask[row] ? v : 0.f;
            ((float*)Cv)[(long)row * N + col] = v;
          } else {
            ((u16*)Cv)[(long)row * N + col] = f2bs(v);
          }
        }
  }
}

// ---------------------------------------------------------------------------
// Fused flash attention: 512 threads = 8 split-K waves per (b,h,32-q tile).
// Register-resident K/V frags with next-iter prefetch, defer-max softmax
// (wave-vote on per-lane local maxima; per-lane partial denominator), 8-way
// LDS combine. XCD-aware block swizzle (33 q-tiles of 2 bh per XCD).
// ---------------------------------------------------------------------------
__global__ __launch_bounds__(512) void attn_mfma(
    const u16* __restrict__ Qb, const u16* __restrict__ Kb,
    const u16* __restrict__ Vt, u16* __restrict__ AO) {
  int i = blockIdx.x;
  int xcd = i & 7, slot = i >> 3;          // 66 slots per XCD
  int bh = (xcd << 1) | (slot >= NQT ? 1 : 0);
  int qt = (slot >= NQT) ? slot - NQT : slot;
  int h = bh & 7;
  int b = bh >> 3;
  int tid = threadIdx.x, w = tid >> 6, lane = tid & 63;
  int g = lane >> 4, li = lane & 15;

  __shared__ float accs[NSPLIT][32][33];
  __shared__ float msh[NSPLIT][32];
  __shared__ float dsh[NSPLIT][32];

  fr qf0, qf1;
  {
    const float QSC = 0.25509836048f;  // (1/sqrt(32)) * log2(e)
#pragma unroll
    for (int qb = 0; qb < 2; ++qb) {
      int qrow = qt * 32 + qb * 16 + li;
      if (qrow >= Q_MAX) qrow = Q_MAX - 1;
      bf16x8 raw = *reinterpret_cast<const bf16x8*>(
          Qb + ((long)(b * Q_MAX + qrow)) * D + h * HD + g * 8);
      fr& qf = qb ? qf1 : qf0;
#pragma unroll
      for (int j = 0; j < 4; ++j)
        qf.i[j] = (int)cvt_pk(bs2f((u16)raw[2 * j]) * QSC,
                              bs2f((u16)raw[2 * j + 1]) * QSC);
    }
  }

  f32x4 acc00 = {}, acc01 = {}, acc10 = {}, acc11 = {};
  float m0 = -1e30f, m1 = -1e30f, den0 = 0.f, den1 = 0.f;
  const f32x4 z = {};

  const u16* kp = Kb + ((long)b * L) * D + h * HD + g * 8;
  const u16* vp = Vt + ((long)(b * H + h)) * HD * (long)L;

  int kstart = w * KCHUNK, kend = kstart + KCHUNK;
  bf16x8 kf0 = *reinterpret_cast<const bf16x8*>(kp + (long)(kstart + li) * D);
  bf16x8 kf1 = *reinterpret_cast<const bf16x8*>(kp + (long)(kstart + 16 + li) * D);
  uint2 va0 = *reinterpret_cast<const uint2*>(vp + (long)li * L + kstart + 4 * g);
  uint2 vb0 = *reinterpret_cast<const uint2*>(vp + (long)li * L + kstart + 16 + 4 * g);
  uint2 va1 = *reinterpret_cast<const uint2*>(vp + (long)(16 + li) * L + kstart + 4 * g);
  uint2 vb1 = *reinterpret_cast<const uint2*>(vp + (long)(16 + li) * L + kstart + 16 + 4 * g);

  for (int kb = kstart; kb < kend; kb += 32) {
    int kn = (kb + 32 < kend) ? kb + 32 : kstart;  // wrapped prefetch addr
    bf16x8 nkf0 = *reinterpret_cast<const bf16x8*>(kp + (long)(kn + li) * D);
    bf16x8 nkf1 = *reinterpret_cast<const bf16x8*>(kp + (long)(kn + 16 + li) * D);
    uint2 nva0 = *reinterpret_cast<const uint2*>(vp + (long)li * L + kn + 4 * g);
    uint2 nvb0 = *reinterpret_cast<const uint2*>(vp + (long)li * L + kn + 16 + 4 * g);
    uint2 nva1 = *reinterpret_cast<const uint2*>(vp + (long)(16 + li) * L + kn + 4 * g);
    uint2 nvb1 = *reinterpret_cast<const uint2*>(vp + (long)(16 + li) * L + kn + 16 + 4 * g);

    f32x4 s00 = __builtin_amdgcn_mfma_f32_16x16x32_bf16(kf0, qf0.h, z, 0, 0, 0);
    f32x4 s10 = __builtin_amdgcn_mfma_f32_16x16x32_bf16(kf1, qf0.h, z, 0, 0, 0);
    f32x4 s01 = __builtin_amdgcn_mfma_f32_16x16x32_bf16(kf0, qf1.h, z, 0, 0, 0);
    f32x4 s11 = __builtin_amdgcn_mfma_f32_16x16x32_bf16(kf1, qf1.h, z, 0, 0, 0);

    // per-lane local maxima (8 keys each)
    float t0 = fmaxf(fmaxf(fmaxf(s00[0], s00[1]), fmaxf(s00[2], s00[3])),
                     fmaxf(fmaxf(s10[0], s10[1]), fmaxf(s10[2], s10[3])));
    float t1 = fmaxf(fmaxf(fmaxf(s01[0], s01[1]), fmaxf(s01[2], s01[3])),
                     fmaxf(fmaxf(s11[0], s11[1]), fmaxf(s11[2], s11[3])));

    if (!__all(t0 <= m0 + 8.f && t1 <= m1 + 8.f)) {
      // full rescale path (rare)
      float T0 = t0, T1 = t1;
      T0 = fmaxf(T0, __shfl_xor(T0, 16, 64));
      T0 = fmaxf(T0, __shfl_xor(T0, 32, 64));
      T1 = fmaxf(T1, __shfl_xor(T1, 16, 64));
      T1 = fmaxf(T1, __shfl_xor(T1, 32, 64));
      float nm0 = fmaxf(m0, T0), nm1 = fmaxf(m1, T1);
      float sc0 = exp2f(m0 - nm0), sc1 = exp2f(m1 - nm1);
      m0 = nm0;
      m1 = nm1;
      den0 *= sc0;
      den1 *= sc1;
#pragma unroll
      for (int r = 0; r < 4; ++r) {
        acc00[r] *= sc0;
        acc10[r] *= sc0;
        acc01[r] *= sc1;
        acc11[r] *= sc1;
      }
    }

    float p00[4], p10[4], p01[4], p11[4];
#pragma unroll
    for (int r = 0; r < 4; ++r) {
      p00[r] = exp2f(s00[r] - m0);
      p10[r] = exp2f(s10[r] - m0);
      p01[r] = exp2f(s01[r] - m1);
      p11[r] = exp2f(s11[r] - m1);
      den0 += p00[r] + p10[r];
      den1 += p01[r] + p11[r];
    }
    fr pf0, pf1;
    pf0.i[0] = (int)cvt_pk(p00[0], p00[1]);
    pf0.i[1] = (int)cvt_pk(p00[2], p00[3]);
    pf0.i[2] = (int)cvt_pk(p10[0], p10[1]);
    pf0.i[3] = (int)cvt_pk(p10[2], p10[3]);
    pf1.i[0] = (int)cvt_pk(p01[0], p01[1]);
    pf1.i[1] = (int)cvt_pk(p01[2], p01[3]);
    pf1.i[2] = (int)cvt_pk(p11[0], p11[1]);
    pf1.i[3] = (int)cvt_pk(p11[2], p11[3]);

    fr v0, v1;
    v0.i = (i32x4){(int)va0.x, (int)va0.y, (int)vb0.x, (int)vb0.y};
    v1.i = (i32x4){(int)va1.x, (int)va1.y, (int)vb1.x, (int)vb1.y};
    acc00 = __builtin_amdgcn_mfma_f32_16x16x32_bf16(v0.h, pf0.h, acc00, 0, 0, 0);
    acc01 = __builtin_amdgcn_mfma_f32_16x16x32_bf16(v0.h, pf1.h, acc01, 0, 0, 0);
    acc10 = __builtin_amdgcn_mfma_f32_16x16x32_bf16(v1.h, pf0.h, acc10, 0, 0, 0);
    acc11 = __builtin_amdgcn_mfma_f32_16x16x32_bf16(v1.h, pf1.h, acc11, 0, 0, 0);

    kf0 = nkf0; kf1 = nkf1;
    va0 = nva0; vb0 = nvb0; va1 = nva1; vb1 = nvb1;
  }

  // reduce per-lane denominators over g
  den0 += __shfl_xor(den0, 16, 64);
  den0 += __shfl_xor(den0, 32, 64);
  den1 += __shfl_xor(den1, 16, 64);
  den1 += __shfl_xor(den1, 32, 64);

#pragma unroll
  for (int r = 0; r < 4; ++r) {
    accs[w][g * 4 + r][li] = acc00[r];
    accs[w][g * 4 + r][16 + li] = acc01[r];
    accs[w][16 + g * 4 + r][li] = acc10[r];
    accs[w][16 + g * 4 + r][16 + li] = acc11[r];
  }
  if (g == 0) {
    msh[w][li] = m0;
    msh[w][16 + li] = m1;
    dsh[w][li] = den0;
    dsh[w][16 + li] = den1;
  }
  __syncthreads();

  // 8-way combine: q = tid>>4 (0..31), ds = tid&15 (d-pair)
  int q = tid >> 4, ds = tid & 15;
  float M = msh[0][q];
#pragma unroll
  for (int ww = 1; ww < NSPLIT; ++ww) M = fmaxf(M, msh[ww][q]);
  float Den = 0.f, wgt[NSPLIT];
#pragma unroll
  for (int ww = 0; ww < NSPLIT; ++ww) {
    wgt[ww] = exp2f(msh[ww][q] - M);
    Den += wgt[ww] * dsh[ww][q];
  }
  float inv = 1.f / Den;
  float o0 = 0.f, o1 = 0.f;
#pragma unroll
  for (int ww = 0; ww < NSPLIT; ++ww) {
    o0 += accs[ww][2 * ds][q] * wgt[ww];
    o1 += accs[ww][2 * ds + 1][q] * wgt[ww];
  }
  int qrow = qt * 32 + q;
  if (qrow < Q_MAX) {
    unsigned pk = cvt_pk(o0 * inv, o1 * inv);
    *reinterpret_cast<unsigned*>(
        AO + ((long)(b * Q_MAX + qrow)) * D + h * HD + 2 * ds) = pk;
  }
}

// ---------------------------------------------------------------------------
__global__ __launch_bounds__(256) void head_kernel(
    const float* __restrict__ enc, const float* __restrict__ hW,
    const float* __restrict__ hb, float* __restrict__ out) {
  int row = blockIdx.x * 4 + (threadIdx.x >> 6);
  int lane = threadIdx.x & 63;
  const float4 a = *reinterpret_cast<const float4*>(enc + (long)row * D + lane * 4);
  float c0 = 0.f, c1 = 0.f, c2 = 0.f;
  const float av[4] = {a.x, a.y, a.z, a.w};
#pragma unroll
  for (int i = 0; i < 4; ++i) {
    int k = lane * 4 + i;
    c0 += av[i] * hW[k * 3];
    c1 += av[i] * hW[k * 3 + 1];
    c2 += av[i] * hW[k * 3 + 2];
  }
#pragma unroll
  for (int off = 32; off; off >>= 1) {
    c0 += __shfl_down(c0, off, 64);
    c1 += __shfl_down(c1, off, 64);
    c2 += __shfl_down(c2, off, 64);
  }
  if (lane == 0) {
    out[(long)row * 3] = c0 + hb[0];
    out[(long)row * 3 + 1] = c1 + hb[1];
    out[(long)row * 3 + 2] = c2 + hb[2];
  }
}

// ---------------------------------------------------------------------------
__global__ __launch_bounds__(64) void overwrite_kernel(
    const float* __restrict__ q_stream, const int* __restrict__ idx,
    const int* __restrict__ mask, const float* __restrict__ hW,
    const float* __restrict__ hb, float* __restrict__ out) {
  int j = blockIdx.x;
  if (!mask[j]) return;
  int b = j / Q_MAX;
  int p = idx[j];
  int lane = threadIdx.x;
  const float* a = q_stream + (long)j * D;
  float a0 = a[lane], a1 = a[lane + 64], a2 = a[lane + 128],
        a3 = a[lane + 192];
  for (int c = 0; c < 3; ++c) {
    float s = a0 * hW[lane * 3 + c] + a1 * hW[(lane + 64) * 3 + c] +
              a2 * hW[(lane + 128) * 3 + c] + a3 * hW[(lane + 192) * 3 + c];
    for (int off = 32; off > 0; off >>= 1) s += __shfl_down(s, off, 64);
    if (lane == 0) out[((long)b * L + p) * 3 + c] = s + hb[c];
  }
}

// ---------------------------------------------------------------------------
extern "C" void kernel_launch(void* const* d_in, const int* in_sizes, int n_in,
                              void* d_out, int out_size, void* d_ws,
                              size_t ws_size, hipStream_t stream) {
  const float* enc = (const float*)d_in[0];
  const float* clog = (const float*)d_in[1];
  const float* ln_q_g = (const float*)d_in[2];
  const float* ln_q_b = (const float*)d_in[3];
  const float* ln_kv_g = (const float*)d_in[4];
  const float* ln_kv_b = (const float*)d_in[5];
  const float* Wq = (const float*)d_in[6];
  const float* bq = (const float*)d_in[7];
  const float* Wk = (const float*)d_in[8];
  const float* bk = (const float*)d_in[9];
  const float* Wv = (const float*)d_in[10];
  const float* bv = (const float*)d_in[11];
  const float* Wo = (const float*)d_in[12];
  const float* bo = (const float*)d_in[13];
  const float* ffn_g = (const float*)d_in[14];
  const float* ffn_b = (const float*)d_in[15];
  const float* W1 = (const float*)d_in[16];
  const float* b1 = (const float*)d_in[17];
  const float* W2 = (const float*)d_in[18];
  const float* b2 = (const float*)d_in[19];
  const float* head_W = (const float*)d_in[20];
  const float* head_b = (const float*)d_in[21];
  float* out = (float*)d_out;

  char* ws = (char*)d_ws;
  float* q_stream = (float*)ws;            ws += (long)QROWS * D * 4;
  u16* kvl0 = (u16*)ws;                    ws += (long)KVROWS * D * 2;
  u16* kvl1 = (u16*)ws;                    ws += (long)KVROWS * D * 2;
  u16* Kbuf = (u16*)ws;                    ws += (long)KVROWS * D * 2;
  u16* Vtbuf = (u16*)ws;                   ws += (long)B * H * HD * L * 2;
  u16* q_ln = (u16*)ws;                    ws += (long)QROWS * D * 2;
  u16* Qbuf = (u16*)ws;                    ws += (long)QROWS * D * 2;
  u16* AObuf = (u16*)ws;                   ws += (long)QROWS * D * 2;
  u16* H1buf = (u16*)ws;                   ws += (long)QROWS * FF * 2;
  u16* WT = (u16*)ws;                      ws += (long)NL * (4 * D * D + 2 * D * FF) * 2;
  float* lnkv_pack = (float*)ws;           ws += 4 * D * 4;
  int* idxbuf = (int*)ws;                  ws += QROWS * 4;
  int* maskbuf = (int*)ws;

  const long DD = (long)D * D, DFF = (long)D * FF;
  const long LSTR = 4 * DD + 2 * DFF;

  transpose_all<<<(int)((NL * LSTR + 255) / 256), 256, 0, stream>>>(
      Wq, Wk, Wv, Wo, W1, W2, WT);
  pack_lnkv<<<(4 * D + 255) / 256, 256, 0, stream>>>(ln_kv_g, ln_kv_b, lnkv_pack);
  ln_kv2<<<KVROWS, 256, 0, stream>>>(enc, kvl0, kvl1, lnkv_pack);
  select_kernel<<<B, 1024, 0, stream>>>(clog, idxbuf, maskbuf);
  gather_kernel<<<QROWS, 256, 0, stream>>>(enc, idxbuf, q_stream);

  for (int l = 0; l < NL; ++l) {
    u16* base = WT + l * LSTR;
    u16* kv_ln = (l == 0) ? kvl0 : kvl1;

    ln_bf16<<<QROWS, 256, 0, stream>>>(q_stream, q_ln, ln_q_g + l * D, ln_q_b + l * D);

    dim3 gKV(D / 64, KVROWS / 64);
    gemm_mfma<0><<<gKV, 256, 0, stream>>>(kv_ln, base, bk + l * D,
                                          (void*)Kbuf, nullptr, nullptr,
                                          KVROWS, D, D);
    gemm_mfma<3><<<gKV, 256, 0, stream>>>(kv_ln, base + DD, bv + l * D,
                                          (void*)Vtbuf, nullptr, nullptr,
                                          KVROWS, D, D);
    dim3 gQ(D / 64, (QROWS + 63) / 64);
    gemm_mfma<0><<<gQ, 256, 0, stream>>>(q_ln, base + 2 * DD, bq + l * D,
                                         (void*)Qbuf, nullptr, nullptr,
                                         QROWS, D, D);

    attn_mfma<<<B * H * NQT, 512, 0, stream>>>(Qbuf, Kbuf, Vtbuf, AObuf);

    gemm_mfma<2><<<gQ, 256, 0, stream>>>(AObuf, base + 3 * DD, bo + l * D,
                                         (void*)q_stream, q_stream, maskbuf,
                                         QROWS, D, D);

    ln_bf16<<<QROWS, 256, 0, stream>>>(q_stream, q_ln, ffn_g + l * D, ffn_b + l * D);
    dim3 gF1(FF / 64, (QROWS + 63) / 64);
    gemm_mfma<1><<<gF1, 256, 0, stream>>>(q_ln, base + 4 * DD, b1 + l * FF,
                                          (void*)H1buf, nullptr, nullptr,
                                          QROWS, FF, D);
    dim3 gF2(D / 64, (QROWS + 63) / 64);
    gemm_mfma<2><<<gF2, 256, 0, stream>>>(H1buf, base + 4 * DD + DFF,
                                          b2 + l * D, (void*)q_stream,
                                          q_stream, maskbuf, QROWS, D, FF);
  }

  head_kernel<<<KVROWS / 4, 256, 0, stream>>>(enc, head_W, head_b, out);
  overwrite_kernel<<<QROWS, 64, 0, stream>>>(q_stream, idxbuf, maskbuf, head_W,
                                             head_b, out);
}

// Round 5
// 270.138 us; speedup vs baseline: 1.2402x; 1.2402x over previous
//
#include <hip/hip_runtime.h>
#include <cmath>

constexpr int B = 2, L = 4096, D = 256, H = 8, NC = 3;
constexpr int TOP_N = 8, R = 32;
constexpr int LS = 1000, LE = 3000;
constexpr int NL = 2;
constexpr int FF = 4 * D;                        // 1024
constexpr int Q_MAX = 2 * TOP_N * (2 * R + 1);   // 1040
constexpr int HD = D / H;                        // 32
constexpr int QROWS = B * Q_MAX;                 // 2080
constexpr int KVROWS = B * L;                    // 8192
constexpr int NQT = (Q_MAX + 31) / 32;           // 33 q-tiles of 32
constexpr int NREG = LE - LS;                    // 2000
constexpr int NSPLIT = 8;                        // split-K waves per block
constexpr int KCHUNK = L / NSPLIT;               // 512 keys per wave

typedef __attribute__((ext_vector_type(8))) short bf16x8;
typedef __attribute__((ext_vector_type(4))) float f32x4;
typedef __attribute__((ext_vector_type(4))) int i32x4;
typedef unsigned short u16;

union fr {
  bf16x8 h;
  i32x4 i;
};

__device__ __forceinline__ u16 f2bs(float f) {
  unsigned int u = __float_as_uint(f);
  unsigned int r = u + 0x7fffu + ((u >> 16) & 1u);
  return (u16)(r >> 16);
}
__device__ __forceinline__ float bs2f(u16 s) {
  return __uint_as_float(((unsigned int)s) << 16);
}
__device__ __forceinline__ float gelu_exact(float x) {
  return 0.5f * x * (1.f + erff(x * 0.70710678118654752440f));
}
__device__ __forceinline__ unsigned cvt_pk(float lo, float hi) {
  unsigned r;
  asm("v_cvt_pk_bf16_f32 %0, %1, %2" : "=v"(r) : "v"(lo), "v"(hi));
  return r;
}

// ---------------------------------------------------------------------------
// Vicinity selection. One 1024-thread block per batch.
// ---------------------------------------------------------------------------
__global__ __launch_bounds__(1024) void select_kernel(
    const float* __restrict__ logits, int* __restrict__ idx_out,
    int* __restrict__ mask_out) {
  int b = blockIdx.x;
  int tid = threadIdx.x;
  __shared__ float vv[2][NREG];
  __shared__ int centers[2 * TOP_N];
  __shared__ unsigned present[L / 32];
  __shared__ float wred[16];
  __shared__ int wredi[16];
  __shared__ int offs[128];
  __shared__ int wtot[2];

  for (int p = tid; p < NREG; p += 1024) {
    const float* lg = logits + ((long)b * L + LS + p) * NC;
    float x0 = lg[0], x1 = lg[1], x2 = lg[2];
    float m = fmaxf(x0, fmaxf(x1, x2));
    float lse = m + logf(expf(x0 - m) + expf(x1 - m) + expf(x2 - m));
    vv[0][p] = x2 - lse;  // don
    vv[1][p] = x1 - lse;  // acc
  }
  if (tid < 128) present[tid] = 0;
  __syncthreads();

  for (int sel = 0; sel < 2; ++sel) {
    for (int t = 0; t < TOP_N; ++t) {
      float bv = -INFINITY;
      int bi = 0x7fffffff;
      for (int p = tid; p < NREG; p += 1024) {
        float x = vv[sel][p];
        if (x > bv || (x == bv && p < bi)) { bv = x; bi = p; }
      }
#pragma unroll
      for (int off = 32; off; off >>= 1) {
        float ov = __shfl_xor(bv, off, 64);
        int oi = __shfl_xor(bi, off, 64);
        if (ov > bv || (ov == bv && oi < bi)) { bv = ov; bi = oi; }
      }
      if ((tid & 63) == 0) { wred[tid >> 6] = bv; wredi[tid >> 6] = bi; }
      __syncthreads();
      if (tid < 64) {
        bv = (tid < 16) ? wred[tid] : -INFINITY;
        bi = (tid < 16) ? wredi[tid] : 0x7fffffff;
#pragma unroll
        for (int off = 8; off; off >>= 1) {
          float ov = __shfl_xor(bv, off, 64);
          int oi = __shfl_xor(bi, off, 64);
          if (ov > bv || (ov == bv && oi < bi)) { bv = ov; bi = oi; }
        }
        if (tid == 0) {
          centers[sel * TOP_N + t] = LS + bi;
          vv[sel][bi] = -INFINITY;
        }
      }
      __syncthreads();
    }
  }

  for (int j = tid; j < Q_MAX; j += 1024) {
    int c = centers[j / (2 * R + 1)];
    int off = j % (2 * R + 1) - R;
    int v = c + off;
    v = v < 0 ? 0 : (v > L - 1 ? L - 1 : v);
    atomicOr(&present[v >> 5], 1u << (v & 31));
  }
  __syncthreads();

  int cnt = (tid < 128) ? __popc(present[tid]) : 0;
  if (tid < 128) {
    int x = cnt;
#pragma unroll
    for (int off = 1; off < 64; off <<= 1) {
      int o = __shfl_up(x, off, 64);
      if ((tid & 63) >= off) x += o;
    }
    if ((tid & 63) == 63) wtot[tid >> 6] = x;
    offs[tid] = x - cnt;
  }
  __syncthreads();
  int total = wtot[0] + wtot[1];
  if (tid < 128) {
    int base = offs[tid] + ((tid >= 64) ? wtot[0] : 0);
    unsigned mword = present[tid];
    while (mword) {
      int i = __ffs(mword) - 1;
      mword &= mword - 1;
      idx_out[b * Q_MAX + base] = tid * 32 + i;
      mask_out[b * Q_MAX + base] = 1;
      ++base;
    }
  }
  for (int j = total + tid; j < Q_MAX; j += 1024) {
    idx_out[b * Q_MAX + j] = L;
    mask_out[b * Q_MAX + j] = 0;
  }
}

// ---------------------------------------------------------------------------
__global__ __launch_bounds__(256) void gather_kernel(
    const float* __restrict__ enc, const int* __restrict__ idx,
    float* __restrict__ q_stream) {
  int row = blockIdx.x;
  int b = row / Q_MAX;
  int p = idx[row];
  float v = 0.f;
  if (p < L) v = enc[((long)b * L + p) * D + threadIdx.x];
  q_stream[(long)row * D + threadIdx.x] = v;
}

// ---------------------------------------------------------------------------
// LayerNorm fp32 in -> bf16 out (single gamma/beta)
// ---------------------------------------------------------------------------
__global__ __launch_bounds__(256) void ln_bf16(
    const float* __restrict__ in, u16* __restrict__ out,
    const float* __restrict__ gg, const float* __restrict__ bb) {
  long row = blockIdx.x;
  int tid = threadIdx.x;
  float x = in[row * D + tid];
  float s1 = x, s2 = x * x;
#pragma unroll
  for (int off = 32; off; off >>= 1) {
    s1 += __shfl_xor(s1, off, 64);
    s2 += __shfl_xor(s2, off, 64);
  }
  __shared__ float p1[4], p2[4];
  int w = tid >> 6;
  if ((tid & 63) == 0) { p1[w] = s1; p2[w] = s2; }
  __syncthreads();
  s1 = p1[0] + p1[1] + p1[2] + p1[3];
  s2 = p2[0] + p2[1] + p2[2] + p2[3];
  float mean = s1 * (1.f / D);
  float var = fmaxf(s2 * (1.f / D) - mean * mean, 0.f);
  float r = rsqrtf(var + 1e-5f);
  out[row * D + tid] = f2bs((x - mean) * r * gg[tid] + bb[tid]);
}

// LayerNorm of enc with BOTH layers' gamma/beta -> two bf16 outputs
__global__ __launch_bounds__(256) void ln_kv2(
    const float* __restrict__ in, u16* __restrict__ o0, u16* __restrict__ o1,
    const float* __restrict__ g) {
  long row = blockIdx.x;
  int tid = threadIdx.x;
  float x = in[row * D + tid];
  float s1 = x, s2 = x * x;
#pragma unroll
  for (int off = 32; off; off >>= 1) {
    s1 += __shfl_xor(s1, off, 64);
    s2 += __shfl_xor(s2, off, 64);
  }
  __shared__ float p1[4], p2[4];
  int w = tid >> 6;
  if ((tid & 63) == 0) { p1[w] = s1; p2[w] = s2; }
  __syncthreads();
  s1 = p1[0] + p1[1] + p1[2] + p1[3];
  s2 = p2[0] + p2[1] + p2[2] + p2[3];
  float mean = s1 * (1.f / D);
  float var = fmaxf(s2 * (1.f / D) - mean * mean, 0.f);
  float r = rsqrtf(var + 1e-5f);
  float xn = (x - mean) * r;
  o0[row * D + tid] = f2bs(xn * g[tid] + g[2 * D + tid]);
  o1[row * D + tid] = f2bs(xn * g[D + tid] + g[3 * D + tid]);
}

__global__ __launch_bounds__(256) void pack_lnkv(
    const float* __restrict__ g, const float* __restrict__ bb,
    float* __restrict__ dst) {
  int t = blockIdx.x * 256 + threadIdx.x;
  if (t < 2 * D) dst[t] = g[t];
  else if (t < 4 * D) dst[t] = bb[t - 2 * D];
}

// ---------------------------------------------------------------------------
// Batched weight transpose+bf16: all NL layers, all 6 matrices, one dispatch.
// ---------------------------------------------------------------------------
__global__ __launch_bounds__(256) void transpose_all(
    const float* __restrict__ Wq_, const float* __restrict__ Wk_,
    const float* __restrict__ Wv_, const float* __restrict__ Wo_,
    const float* __restrict__ W1_, const float* __restrict__ W2_,
    u16* __restrict__ WT) {
  const long DD = (long)D * D, DFF = (long)D * FF;
  const long LSTR = 4 * DD + 2 * DFF;
  long t = (long)blockIdx.x * 256 + threadIdx.x;
  if (t >= NL * LSTR) return;
  int l = (int)(t / LSTR);
  long r = t - (long)l * LSTR;
  const float* src;
  long dstbase, e;
  int K_, N_;
  if (r < 4 * DD) {
    int which = (int)(r >> 16);
    e = r & (DD - 1);
    K_ = D; N_ = D;
    src = (which == 0 ? Wk_ : which == 1 ? Wv_ : which == 2 ? Wq_ : Wo_) +
          (long)l * DD;
    dstbase = l * LSTR + which * DD;
  } else if (r < 4 * DD + DFF) {
    e = r - 4 * DD;
    K_ = D; N_ = FF;
    src = W1_ + (long)l * DFF;
    dstbase = l * LSTR + 4 * DD;
  } else {
    e = r - 4 * DD - DFF;
    K_ = FF; N_ = D;
    src = W2_ + (long)l * DFF;
    dstbase = l * LSTR + 4 * DD + DFF;
  }
  int k = (int)(e / N_), n = (int)(e % N_);
  WT[dstbase + (long)n * K_ + k] = f2bs(src[e]);
}

// ---------------------------------------------------------------------------
// bf16 MFMA GEMM (64x64 tile, BK=32, 4 waves).
// EPI 0: bias->bf16 [row][col]
// EPI 1: gelu->bf16 [row][col]
// EPI 2: resid+mask->f32 [row][col]
// EPI 3: bias->bf16 Vh[b][h][key/32][d][key%32]   (32-key contiguous tiles)
// EPI 4: bias->bf16 Kh[b][h][key][d]              (64B contiguous key rows)
// ---------------------------------------------------------------------------
template <int EPI>
__global__ __launch_bounds__(256) void gemm_mfma(
    const u16* __restrict__ A, const u16* __restrict__ BT,
    const float* __restrict__ bias, void* __restrict__ Cv,
    const float* __restrict__ resid, const int* __restrict__ mask, int M,
    int N, int K) {
  __shared__ short As[64][40];
  __shared__ short Bs[64][40];
  int bm = blockIdx.y * 64, bn = blockIdx.x * 64;
  int tid = threadIdx.x;
  int lane = tid & 63, w = tid >> 6;
  int g = lane >> 4, li = lane & 15;
  int wr = w >> 1, wc = w & 1;
  f32x4 acc[2][2] = {};

  int srow = tid >> 2, skc = (tid & 3) * 8;
  for (int k0 = 0; k0 < K; k0 += 32) {
    {
      int grow = bm + srow;
      bf16x8 av = {};
      if (grow < M)
        av = *reinterpret_cast<const bf16x8*>(A + (long)grow * K + k0 + skc);
      *reinterpret_cast<bf16x8*>(&As[srow][skc]) = av;
      bf16x8 bv = *reinterpret_cast<const bf16x8*>(
          BT + (long)(bn + srow) * K + k0 + skc);
      *reinterpret_cast<bf16x8*>(&Bs[srow][skc]) = bv;
    }
    __syncthreads();
    bf16x8 a0 = *reinterpret_cast<const bf16x8*>(&As[wr * 32 + li][g * 8]);
    bf16x8 a1 = *reinterpret_cast<const bf16x8*>(&As[wr * 32 + 16 + li][g * 8]);
    bf16x8 b0 = *reinterpret_cast<const bf16x8*>(&Bs[wc * 32 + li][g * 8]);
    bf16x8 b1 = *reinterpret_cast<const bf16x8*>(&Bs[wc * 32 + 16 + li][g * 8]);
    acc[0][0] = __builtin_amdgcn_mfma_f32_16x16x32_bf16(a0, b0, acc[0][0], 0, 0, 0);
    acc[0][1] = __builtin_amdgcn_mfma_f32_16x16x32_bf16(a0, b1, acc[0][1], 0, 0, 0);
    acc[1][0] = __builtin_amdgcn_mfma_f32_16x16x32_bf16(a1, b0, acc[1][0], 0, 0, 0);
    acc[1][1] = __builtin_amdgcn_mfma_f32_16x16x32_bf16(a1, b1, acc[1][1], 0, 0, 0);
    __syncthreads();
  }

  if constexpr (EPI == 3) {
    // Vh: stage d-major (transposed), write 32-key-tile rows of 8 keys
    __shared__ u16 Ct[64][72];
#pragma unroll
    for (int mr = 0; mr < 2; ++mr)
#pragma unroll
      for (int nr = 0; nr < 2; ++nr)
#pragma unroll
        for (int r = 0; r < 4; ++r) {
          int rowL = wr * 32 + mr * 16 + g * 4 + r;
          int colL = wc * 32 + nr * 16 + li;
          Ct[colL][rowL] = f2bs(acc[mr][nr][r] + bias[bn + colL]);
        }
    __syncthreads();
    int b2 = bm >> 12;
#pragma unroll
    for (int p = 0; p < 2; ++p) {
      int colL = (tid >> 3) + p * 32;
      int rem = tid & 7;
      int kb = rem >> 2, k8 = (rem & 3) * 8;
      int gcol = bn + colL;
      int hh = gcol >> 5, dd = gcol & (HD - 1);
      int kb32 = ((bm & (L - 1)) >> 5) + kb;
      u16* dst = (u16*)Cv +
                 (((long)(b2 * H + hh) * (L / 32) + kb32) * 1024 + dd * 32 + k8);
      *reinterpret_cast<bf16x8*>(dst) =
          *reinterpret_cast<const bf16x8*>(&Ct[colL][kb * 32 + k8]);
    }
  } else if constexpr (EPI == 4) {
    // Kh: stage normal orientation, write 64B contiguous key rows
    __shared__ u16 Ct[64][72];
#pragma unroll
    for (int mr = 0; mr < 2; ++mr)
#pragma unroll
      for (int nr = 0; nr < 2; ++nr)
#pragma unroll
        for (int r = 0; r < 4; ++r) {
          int rowL = wr * 32 + mr * 16 + g * 4 + r;
          int colL = wc * 32 + nr * 16 + li;
          Ct[rowL][colL] = f2bs(acc[mr][nr][r] + bias[bn + colL]);
        }
    __syncthreads();
#pragma unroll
    for (int p = 0; p < 2; ++p) {
      int rowL = (tid >> 3) + p * 32;
      int c8 = (tid & 7) * 8;
      int grow = bm + rowL;
      int b2 = grow >> 12, key = grow & (L - 1);
      int gcol = bn + c8;
      int hh = gcol >> 5, dd = gcol & (HD - 1);
      u16* dst = (u16*)Cv + (((long)(b2 * H + hh) * L + key) * 32 + dd);
      *reinterpret_cast<bf16x8*>(dst) =
          *reinterpret_cast<const bf16x8*>(&Ct[rowL][c8]);
    }
  } else {
#pragma unroll
    for (int mr = 0; mr < 2; ++mr)
#pragma unroll
      for (int nr = 0; nr < 2; ++nr)
#pragma unroll
        for (int r = 0; r < 4; ++r) {
          int row = bm + wr * 32 + mr * 16 + g * 4 + r;
          int col = bn + wc * 32 + nr * 16 + li;
          if (row >= M) continue;
          float v = acc[mr][nr][r] + bias[col];
          if (EPI == 1) v = gelu_exact(v);
          if (EPI == 2) {
            v += resid[(long)row * N + col];
            v = mask[row] ? v : 0.f;
            ((float*)Cv)[(long)row * N + col] = v;
          } else {
            ((u16*)Cv)[(long)row * N + col] = f2bs(v);
          }
        }
  }
}

// ---------------------------------------------------------------------------
// Fused flash attention: 512 threads = 8 split-K waves per (b,h,32-q tile).
// K/V read from per-head CONTIGUOUS 2KB tiles (Kh/Vh layouts) -> fully
// coalesced; register prefetch one tile ahead; defer-max softmax; 8-way LDS
// combine; XCD-aware block swizzle.
// ---------------------------------------------------------------------------
__global__ __launch_bounds__(512) void attn_mfma(
    const u16* __restrict__ Qb, const u16* __restrict__ Kh,
    const u16* __restrict__ Vh, u16* __restrict__ AO) {
  int i = blockIdx.x;
  int xcd = i & 7, slot = i >> 3;          // 66 slots per XCD
  int bh = (xcd << 1) | (slot >= NQT ? 1 : 0);
  int qt = (slot >= NQT) ? slot - NQT : slot;
  int h = bh & 7;
  int b = bh >> 3;
  int tid = threadIdx.x, w = tid >> 6, lane = tid & 63;
  int g = lane >> 4, li = lane & 15;

  __shared__ float accs[NSPLIT][32][33];
  __shared__ float msh[NSPLIT][32];
  __shared__ float dsh[NSPLIT][32];

  fr qf0, qf1;
  {
    const float QSC = 0.25509836048f;  // (1/sqrt(32)) * log2(e)
#pragma unroll
    for (int qb = 0; qb < 2; ++qb) {
      int qrow = qt * 32 + qb * 16 + li;
      if (qrow >= Q_MAX) qrow = Q_MAX - 1;
      bf16x8 raw = *reinterpret_cast<const bf16x8*>(
          Qb + ((long)(b * Q_MAX + qrow)) * D + h * HD + g * 8);
      fr& qf = qb ? qf1 : qf0;
#pragma unroll
      for (int j = 0; j < 4; ++j)
        qf.i[j] = (int)cvt_pk(bs2f((u16)raw[2 * j]) * QSC,
                              bs2f((u16)raw[2 * j + 1]) * QSC);
    }
  }

  f32x4 acc00 = {}, acc01 = {}, acc10 = {}, acc11 = {};
  float m0 = -1e30f, m1 = -1e30f, den0 = 0.f, den1 = 0.f;
  const f32x4 z = {};

  // both Kh and Vh advance 1024 shorts (2KB) per 32 keys
  const u16* kbase = Kh + ((long)(b * H + h) * L) * HD;
  const u16* vbase = Vh + ((long)(b * H + h) * L) * HD;
  int koff0 = li * 32 + g * 8, koff1 = (16 + li) * 32 + g * 8;
  int va0o = li * 32 + 4 * g, vb0o = li * 32 + 16 + 4 * g;
  int va1o = (16 + li) * 32 + 4 * g, vb1o = (16 + li) * 32 + 16 + 4 * g;

  int kstart = w * KCHUNK, kend = kstart + KCHUNK;
  const u16* kt = kbase + (long)kstart * HD;
  const u16* vt = vbase + (long)kstart * HD;

  bf16x8 kf0 = *reinterpret_cast<const bf16x8*>(kt + koff0);
  bf16x8 kf1 = *reinterpret_cast<const bf16x8*>(kt + koff1);
  uint2 va0 = *reinterpret_cast<const uint2*>(vt + va0o);
  uint2 vb0 = *reinterpret_cast<const uint2*>(vt + vb0o);
  uint2 va1 = *reinterpret_cast<const uint2*>(vt + va1o);
  uint2 vb1 = *reinterpret_cast<const uint2*>(vt + vb1o);

  for (int kb = kstart; kb < kend; kb += 32) {
    // prefetch next tile (wrap to kstart on last iter to stay in-bounds)
    const u16* ktn = (kb + 32 < kend) ? kt + 1024 : kbase + (long)kstart * HD;
    const u16* vtn = (kb + 32 < kend) ? vt + 1024 : vbase + (long)kstart * HD;
    bf16x8 nkf0 = *reinterpret_cast<const bf16x8*>(ktn + koff0);
    bf16x8 nkf1 = *reinterpret_cast<const bf16x8*>(ktn + koff1);
    uint2 nva0 = *reinterpret_cast<const uint2*>(vtn + va0o);
    uint2 nvb0 = *reinterpret_cast<const uint2*>(vtn + vb0o);
    uint2 nva1 = *reinterpret_cast<const uint2*>(vtn + va1o);
    uint2 nvb1 = *reinterpret_cast<const uint2*>(vtn + vb1o);

    f32x4 s00 = __builtin_amdgcn_mfma_f32_16x16x32_bf16(kf0, qf0.h, z, 0, 0, 0);
    f32x4 s10 = __builtin_amdgcn_mfma_f32_16x16x32_bf16(kf1, qf0.h, z, 0, 0, 0);
    f32x4 s01 = __builtin_amdgcn_mfma_f32_16x16x32_bf16(kf0, qf1.h, z, 0, 0, 0);
    f32x4 s11 = __builtin_amdgcn_mfma_f32_16x16x32_bf16(kf1, qf1.h, z, 0, 0, 0);

    float t0 = fmaxf(fmaxf(fmaxf(s00[0], s00[1]), fmaxf(s00[2], s00[3])),
                     fmaxf(fmaxf(s10[0], s10[1]), fmaxf(s10[2], s10[3])));
    float t1 = fmaxf(fmaxf(fmaxf(s01[0], s01[1]), fmaxf(s01[2], s01[3])),
                     fmaxf(fmaxf(s11[0], s11[1]), fmaxf(s11[2], s11[3])));

    if (!__all(t0 <= m0 + 8.f && t1 <= m1 + 8.f)) {
      float T0 = t0, T1 = t1;
      T0 = fmaxf(T0, __shfl_xor(T0, 16, 64));
      T0 = fmaxf(T0, __shfl_xor(T0, 32, 64));
      T1 = fmaxf(T1, __shfl_xor(T1, 16, 64));
      T1 = fmaxf(T1, __shfl_xor(T1, 32, 64));
      float nm0 = fmaxf(m0, T0), nm1 = fmaxf(m1, T1);
      float sc0 = exp2f(m0 - nm0), sc1 = exp2f(m1 - nm1);
      m0 = nm0;
      m1 = nm1;
      den0 *= sc0;
      den1 *= sc1;
#pragma unroll
      for (int r = 0; r < 4; ++r) {
        acc00[r] *= sc0;
        acc10[r] *= sc0;
        acc01[r] *= sc1;
        acc11[r] *= sc1;
      }
    }

    float p00[4], p10[4], p01[4], p11[4];
#pragma unroll
    for (int r = 0; r < 4; ++r) {
      p00[r] = exp2f(s00[r] - m0);
      p10[r] = exp2f(s10[r] - m0);
      p01[r] = exp2f(s01[r] - m1);
      p11[r] = exp2f(s11[r] - m1);
      den0 += p00[r] + p10[r];
      den1 += p01[r] + p11[r];
    }
    fr pf0, pf1;
    pf0.i[0] = (int)cvt_pk(p00[0], p00[1]);
    pf0.i[1] = (int)cvt_pk(p00[2], p00[3]);
    pf0.i[2] = (int)cvt_pk(p10[0], p10[1]);
    pf0.i[3] = (int)cvt_pk(p10[2], p10[3]);
    pf1.i[0] = (int)cvt_pk(p01[0], p01[1]);
    pf1.i[1] = (int)cvt_pk(p01[2], p01[3]);
    pf1.i[2] = (int)cvt_pk(p11[0], p11[1]);
    pf1.i[3] = (int)cvt_pk(p11[2], p11[3]);

    fr v0, v1;
    v0.i = (i32x4){(int)va0.x, (int)va0.y, (int)vb0.x, (int)vb0.y};
    v1.i = (i32x4){(int)va1.x, (int)va1.y, (int)vb1.x, (int)vb1.y};
    acc00 = __builtin_amdgcn_mfma_f32_16x16x32_bf16(v0.h, pf0.h, acc00, 0, 0, 0);
    acc01 = __builtin_amdgcn_mfma_f32_16x16x32_bf16(v0.h, pf1.h, acc01, 0, 0, 0);
    acc10 = __builtin_amdgcn_mfma_f32_16x16x32_bf16(v1.h, pf0.h, acc10, 0, 0, 0);
    acc11 = __builtin_amdgcn_mfma_f32_16x16x32_bf16(v1.h, pf1.h, acc11, 0, 0, 0);

    kf0 = nkf0; kf1 = nkf1;
    va0 = nva0; vb0 = nvb0; va1 = nva1; vb1 = nvb1;
    kt += 1024;
    vt += 1024;
  }

  den0 += __shfl_xor(den0, 16, 64);
  den0 += __shfl_xor(den0, 32, 64);
  den1 += __shfl_xor(den1, 16, 64);
  den1 += __shfl_xor(den1, 32, 64);

#pragma unroll
  for (int r = 0; r < 4; ++r) {
    accs[w][g * 4 + r][li] = acc00[r];
    accs[w][g * 4 + r][16 + li] = acc01[r];
    accs[w][16 + g * 4 + r][li] = acc10[r];
    accs[w][16 + g * 4 + r][16 + li] = acc11[r];
  }
  if (g == 0) {
    msh[w][li] = m0;
    msh[w][16 + li] = m1;
    dsh[w][li] = den0;
    dsh[w][16 + li] = den1;
  }
  __syncthreads();

  int q = tid >> 4, ds = tid & 15;
  float M = msh[0][q];
#pragma unroll
  for (int ww = 1; ww < NSPLIT; ++ww) M = fmaxf(M, msh[ww][q]);
  float Den = 0.f, wgt[NSPLIT];
#pragma unroll
  for (int ww = 0; ww < NSPLIT; ++ww) {
    wgt[ww] = exp2f(msh[ww][q] - M);
    Den += wgt[ww] * dsh[ww][q];
  }
  float inv = 1.f / Den;
  float o0 = 0.f, o1 = 0.f;
#pragma unroll
  for (int ww = 0; ww < NSPLIT; ++ww) {
    o0 += accs[ww][2 * ds][q] * wgt[ww];
    o1 += accs[ww][2 * ds + 1][q] * wgt[ww];
  }
  int qrow = qt * 32 + q;
  if (qrow < Q_MAX) {
    unsigned pk = cvt_pk(o0 * inv, o1 * inv);
    *reinterpret_cast<unsigned*>(
        AO + ((long)(b * Q_MAX + qrow)) * D + h * HD + 2 * ds) = pk;
  }
}

// ---------------------------------------------------------------------------
__global__ __launch_bounds__(256) void head_kernel(
    const float* __restrict__ enc, const float* __restrict__ hW,
    const float* __restrict__ hb, float* __restrict__ out) {
  int row = blockIdx.x * 4 + (threadIdx.x >> 6);
  int lane = threadIdx.x & 63;
  const float4 a = *reinterpret_cast<const float4*>(enc + (long)row * D + lane * 4);
  float c0 = 0.f, c1 = 0.f, c2 = 0.f;
  const float av[4] = {a.x, a.y, a.z, a.w};
#pragma unroll
  for (int i = 0; i < 4; ++i) {
    int k = lane * 4 + i;
    c0 += av[i] * hW[k * 3];
    c1 += av[i] * hW[k * 3 + 1];
    c2 += av[i] * hW[k * 3 + 2];
  }
#pragma unroll
  for (int off = 32; off; off >>= 1) {
    c0 += __shfl_down(c0, off, 64);
    c1 += __shfl_down(c1, off, 64);
    c2 += __shfl_down(c2, off, 64);
  }
  if (lane == 0) {
    out[(long)row * 3] = c0 + hb[0];
    out[(long)row * 3 + 1] = c1 + hb[1];
    out[(long)row * 3 + 2] = c2 + hb[2];
  }
}

// ---------------------------------------------------------------------------
__global__ __launch_bounds__(64) void overwrite_kernel(
    const float* __restrict__ q_stream, const int* __restrict__ idx,
    const int* __restrict__ mask, const float* __restrict__ hW,
    const float* __restrict__ hb, float* __restrict__ out) {
  int j = blockIdx.x;
  if (!mask[j]) return;
  int b = j / Q_MAX;
  int p = idx[j];
  int lane = threadIdx.x;
  const float* a = q_stream + (long)j * D;
  float a0 = a[lane], a1 = a[lane + 64], a2 = a[lane + 128],
        a3 = a[lane + 192];
  for (int c = 0; c < 3; ++c) {
    float s = a0 * hW[lane * 3 + c] + a1 * hW[(lane + 64) * 3 + c] +
              a2 * hW[(lane + 128) * 3 + c] + a3 * hW[(lane + 192) * 3 + c];
    for (int off = 32; off > 0; off >>= 1) s += __shfl_down(s, off, 64);
    if (lane == 0) out[((long)b * L + p) * 3 + c] = s + hb[c];
  }
}

// ---------------------------------------------------------------------------
extern "C" void kernel_launch(void* const* d_in, const int* in_sizes, int n_in,
                              void* d_out, int out_size, void* d_ws,
                              size_t ws_size, hipStream_t stream) {
  const float* enc = (const float*)d_in[0];
  const float* clog = (const float*)d_in[1];
  const float* ln_q_g = (const float*)d_in[2];
  const float* ln_q_b = (const float*)d_in[3];
  const float* ln_kv_g = (const float*)d_in[4];
  const float* ln_kv_b = (const float*)d_in[5];
  const float* Wq = (const float*)d_in[6];
  const float* bq = (const float*)d_in[7];
  const float* Wk = (const float*)d_in[8];
  const float* bk = (const float*)d_in[9];
  const float* Wv = (const float*)d_in[10];
  const float* bv = (const float*)d_in[11];
  const float* Wo = (const float*)d_in[12];
  const float* bo = (const float*)d_in[13];
  const float* ffn_g = (const float*)d_in[14];
  const float* ffn_b = (const float*)d_in[15];
  const float* W1 = (const float*)d_in[16];
  const float* b1 = (const float*)d_in[17];
  const float* W2 = (const float*)d_in[18];
  const float* b2 = (const float*)d_in[19];
  const float* head_W = (const float*)d_in[20];
  const float* head_b = (const float*)d_in[21];
  float* out = (float*)d_out;

  char* ws = (char*)d_ws;
  float* q_stream = (float*)ws;            ws += (long)QROWS * D * 4;
  u16* kvl0 = (u16*)ws;                    ws += (long)KVROWS * D * 2;
  u16* kvl1 = (u16*)ws;                    ws += (long)KVROWS * D * 2;
  u16* Khbuf = (u16*)ws;                   ws += (long)B * H * L * HD * 2;
  u16* Vhbuf = (u16*)ws;                   ws += (long)B * H * L * HD * 2;
  u16* q_ln = (u16*)ws;                    ws += (long)QROWS * D * 2;
  u16* Qbuf = (u16*)ws;                    ws += (long)QROWS * D * 2;
  u16* AObuf = (u16*)ws;                   ws += (long)QROWS * D * 2;
  u16* H1buf = (u16*)ws;                   ws += (long)QROWS * FF * 2;
  u16* WT = (u16*)ws;                      ws += (long)NL * (4 * D * D + 2 * D * FF) * 2;
  float* lnkv_pack = (float*)ws;           ws += 4 * D * 4;
  int* idxbuf = (int*)ws;                  ws += QROWS * 4;
  int* maskbuf = (int*)ws;

  const long DD = (long)D * D, DFF = (long)D * FF;
  const long LSTR = 4 * DD + 2 * DFF;

  transpose_all<<<(int)((NL * LSTR + 255) / 256), 256, 0, stream>>>(
      Wq, Wk, Wv, Wo, W1, W2, WT);
  pack_lnkv<<<(4 * D + 255) / 256, 256, 0, stream>>>(ln_kv_g, ln_kv_b, lnkv_pack);
  ln_kv2<<<KVROWS, 256, 0, stream>>>(enc, kvl0, kvl1, lnkv_pack);
  select_kernel<<<B, 1024, 0, stream>>>(clog, idxbuf, maskbuf);
  gather_kernel<<<QROWS, 256, 0, stream>>>(enc, idxbuf, q_stream);

  for (int l = 0; l < NL; ++l) {
    u16* base = WT + l * LSTR;
    u16* kv_ln = (l == 0) ? kvl0 : kvl1;

    ln_bf16<<<QROWS, 256, 0, stream>>>(q_stream, q_ln, ln_q_g + l * D, ln_q_b + l * D);

    dim3 gKV(D / 64, KVROWS / 64);
    gemm_mfma<4><<<gKV, 256, 0, stream>>>(kv_ln, base, bk + l * D,
                                          (void*)Khbuf, nullptr, nullptr,
                                          KVROWS, D, D);
    gemm_mfma<3><<<gKV, 256, 0, stream>>>(kv_ln, base + DD, bv + l * D,
                                          (void*)Vhbuf, nullptr, nullptr,
                                          KVROWS, D, D);
    dim3 gQ(D / 64, (QROWS + 63) / 64);
    gemm_mfma<0><<<gQ, 256, 0, stream>>>(q_ln, base + 2 * DD, bq + l * D,
                                         (void*)Qbuf, nullptr, nullptr,
                                         QROWS, D, D);

    attn_mfma<<<B * H * NQT, 512, 0, stream>>>(Qbuf, Khbuf, Vhbuf, AObuf);

    gemm_mfma<2><<<gQ, 256, 0, stream>>>(AObuf, base + 3 * DD, bo + l * D,
                                         (void*)q_stream, q_stream, maskbuf,
                                         QROWS, D, D);

    ln_bf16<<<QROWS, 256, 0, stream>>>(q_stream, q_ln, ffn_g + l * D, ffn_b + l * D);
    dim3 gF1(FF / 64, (QROWS + 63) / 64);
    gemm_mfma<1><<<gF1, 256, 0, stream>>>(q_ln, base + 4 * DD, b1 + l * FF,
                                          (void*)H1buf, nullptr, nullptr,
                                          QROWS, FF, D);
    dim3 gF2(D / 64, (QROWS + 63) / 64);
    gemm_mfma<2><<<gF2, 256, 0, stream>>>(H1buf, base + 4 * DD + DFF,
                                          b2 + l * D, (void*)q_stream,
                                          q_stream, maskbuf, QROWS, D, FF);
  }

  head_kernel<<<KVROWS / 4, 256, 0, stream>>>(enc, head_W, head_b, out);
  overwrite_kernel<<<QROWS, 64, 0, stream>>>(q_stream, idxbuf, maskbuf, head_W,
                                             head_b, out);
}

// Round 6
// 263.794 us; speedup vs baseline: 1.2700x; 1.0240x over previous
//
#include <hip/hip_runtime.h>
#include <cmath>

constexpr int B = 2, L = 4096, D = 256, H = 8, NC = 3;
constexpr int TOP_N = 8, R = 32;
constexpr int LS = 1000, LE = 3000;
constexpr int NL = 2;
constexpr int FF = 4 * D;                        // 1024
constexpr int Q_MAX = 2 * TOP_N * (2 * R + 1);   // 1040
constexpr int HD = D / H;                        // 32
constexpr int QROWS = B * Q_MAX;                 // 2080
constexpr int KVROWS = B * L;                    // 8192
constexpr int NQT = (Q_MAX + 31) / 32;           // 33 q-tiles of 32
constexpr int NREG = LE - LS;                    // 2000
constexpr int NSPLIT = 4;                        // split-K waves per block
constexpr int KCHUNK = L / NSPLIT;               // 1024 keys per wave
constexpr int NT = KCHUNK / 32;                  // 32 iterations

typedef __attribute__((ext_vector_type(8))) short bf16x8;
typedef __attribute__((ext_vector_type(4))) float f32x4;
typedef __attribute__((ext_vector_type(4))) int i32x4;
typedef unsigned short u16;

union fr {
  bf16x8 h;
  i32x4 i;
};

__device__ __forceinline__ u16 f2bs(float f) {
  unsigned int u = __float_as_uint(f);
  unsigned int r = u + 0x7fffu + ((u >> 16) & 1u);
  return (u16)(r >> 16);
}
__device__ __forceinline__ float bs2f(u16 s) {
  return __uint_as_float(((unsigned int)s) << 16);
}
__device__ __forceinline__ float gelu_exact(float x) {
  return 0.5f * x * (1.f + erff(x * 0.70710678118654752440f));
}
__device__ __forceinline__ unsigned cvt_pk(float lo, float hi) {
  unsigned r;
  asm("v_cvt_pk_bf16_f32 %0, %1, %2" : "=v"(r) : "v"(lo), "v"(hi));
  return r;
}

#define GLL16(gsrc, ldst)                                                   \
  __builtin_amdgcn_global_load_lds(                                         \
      (const __attribute__((address_space(1))) unsigned int*)(gsrc),        \
      (__attribute__((address_space(3))) unsigned int*)(ldst), 16, 0, 0)

// ---------------------------------------------------------------------------
// Vicinity selection. One 1024-thread block per batch.
// ---------------------------------------------------------------------------
__global__ __launch_bounds__(1024) void select_kernel(
    const float* __restrict__ logits, int* __restrict__ idx_out,
    int* __restrict__ mask_out) {
  int b = blockIdx.x;
  int tid = threadIdx.x;
  __shared__ float vv[2][NREG];
  __shared__ int centers[2 * TOP_N];
  __shared__ unsigned present[L / 32];
  __shared__ float wred[16];
  __shared__ int wredi[16];
  __shared__ int offs[128];
  __shared__ int wtot[2];

  for (int p = tid; p < NREG; p += 1024) {
    const float* lg = logits + ((long)b * L + LS + p) * NC;
    float x0 = lg[0], x1 = lg[1], x2 = lg[2];
    float m = fmaxf(x0, fmaxf(x1, x2));
    float lse = m + logf(expf(x0 - m) + expf(x1 - m) + expf(x2 - m));
    vv[0][p] = x2 - lse;  // don
    vv[1][p] = x1 - lse;  // acc
  }
  if (tid < 128) present[tid] = 0;
  __syncthreads();

  for (int sel = 0; sel < 2; ++sel) {
    for (int t = 0; t < TOP_N; ++t) {
      float bv = -INFINITY;
      int bi = 0x7fffffff;
      for (int p = tid; p < NREG; p += 1024) {
        float x = vv[sel][p];
        if (x > bv || (x == bv && p < bi)) { bv = x; bi = p; }
      }
#pragma unroll
      for (int off = 32; off; off >>= 1) {
        float ov = __shfl_xor(bv, off, 64);
        int oi = __shfl_xor(bi, off, 64);
        if (ov > bv || (ov == bv && oi < bi)) { bv = ov; bi = oi; }
      }
      if ((tid & 63) == 0) { wred[tid >> 6] = bv; wredi[tid >> 6] = bi; }
      __syncthreads();
      if (tid < 64) {
        bv = (tid < 16) ? wred[tid] : -INFINITY;
        bi = (tid < 16) ? wredi[tid] : 0x7fffffff;
#pragma unroll
        for (int off = 8; off; off >>= 1) {
          float ov = __shfl_xor(bv, off, 64);
          int oi = __shfl_xor(bi, off, 64);
          if (ov > bv || (ov == bv && oi < bi)) { bv = ov; bi = oi; }
        }
        if (tid == 0) {
          centers[sel * TOP_N + t] = LS + bi;
          vv[sel][bi] = -INFINITY;
        }
      }
      __syncthreads();
    }
  }

  for (int j = tid; j < Q_MAX; j += 1024) {
    int c = centers[j / (2 * R + 1)];
    int off = j % (2 * R + 1) - R;
    int v = c + off;
    v = v < 0 ? 0 : (v > L - 1 ? L - 1 : v);
    atomicOr(&present[v >> 5], 1u << (v & 31));
  }
  __syncthreads();

  int cnt = (tid < 128) ? __popc(present[tid]) : 0;
  if (tid < 128) {
    int x = cnt;
#pragma unroll
    for (int off = 1; off < 64; off <<= 1) {
      int o = __shfl_up(x, off, 64);
      if ((tid & 63) >= off) x += o;
    }
    if ((tid & 63) == 63) wtot[tid >> 6] = x;
    offs[tid] = x - cnt;
  }
  __syncthreads();
  int total = wtot[0] + wtot[1];
  if (tid < 128) {
    int base = offs[tid] + ((tid >= 64) ? wtot[0] : 0);
    unsigned mword = present[tid];
    while (mword) {
      int i = __ffs(mword) - 1;
      mword &= mword - 1;
      idx_out[b * Q_MAX + base] = tid * 32 + i;
      mask_out[b * Q_MAX + base] = 1;
      ++base;
    }
  }
  for (int j = total + tid; j < Q_MAX; j += 1024) {
    idx_out[b * Q_MAX + j] = L;
    mask_out[b * Q_MAX + j] = 0;
  }
}

// ---------------------------------------------------------------------------
__global__ __launch_bounds__(256) void gather_kernel(
    const float* __restrict__ enc, const int* __restrict__ idx,
    float* __restrict__ q_stream) {
  int row = blockIdx.x;
  int b = row / Q_MAX;
  int p = idx[row];
  float v = 0.f;
  if (p < L) v = enc[((long)b * L + p) * D + threadIdx.x];
  q_stream[(long)row * D + threadIdx.x] = v;
}

// ---------------------------------------------------------------------------
__global__ __launch_bounds__(256) void ln_bf16(
    const float* __restrict__ in, u16* __restrict__ out,
    const float* __restrict__ gg, const float* __restrict__ bb) {
  long row = blockIdx.x;
  int tid = threadIdx.x;
  float x = in[row * D + tid];
  float s1 = x, s2 = x * x;
#pragma unroll
  for (int off = 32; off; off >>= 1) {
    s1 += __shfl_xor(s1, off, 64);
    s2 += __shfl_xor(s2, off, 64);
  }
  __shared__ float p1[4], p2[4];
  int w = tid >> 6;
  if ((tid & 63) == 0) { p1[w] = s1; p2[w] = s2; }
  __syncthreads();
  s1 = p1[0] + p1[1] + p1[2] + p1[3];
  s2 = p2[0] + p2[1] + p2[2] + p2[3];
  float mean = s1 * (1.f / D);
  float var = fmaxf(s2 * (1.f / D) - mean * mean, 0.f);
  float r = rsqrtf(var + 1e-5f);
  out[row * D + tid] = f2bs((x - mean) * r * gg[tid] + bb[tid]);
}

__global__ __launch_bounds__(256) void ln_kv2(
    const float* __restrict__ in, u16* __restrict__ o0, u16* __restrict__ o1,
    const float* __restrict__ g) {
  long row = blockIdx.x;
  int tid = threadIdx.x;
  float x = in[row * D + tid];
  float s1 = x, s2 = x * x;
#pragma unroll
  for (int off = 32; off; off >>= 1) {
    s1 += __shfl_xor(s1, off, 64);
    s2 += __shfl_xor(s2, off, 64);
  }
  __shared__ float p1[4], p2[4];
  int w = tid >> 6;
  if ((tid & 63) == 0) { p1[w] = s1; p2[w] = s2; }
  __syncthreads();
  s1 = p1[0] + p1[1] + p1[2] + p1[3];
  s2 = p2[0] + p2[1] + p2[2] + p2[3];
  float mean = s1 * (1.f / D);
  float var = fmaxf(s2 * (1.f / D) - mean * mean, 0.f);
  float r = rsqrtf(var + 1e-5f);
  float xn = (x - mean) * r;
  o0[row * D + tid] = f2bs(xn * g[tid] + g[2 * D + tid]);
  o1[row * D + tid] = f2bs(xn * g[D + tid] + g[3 * D + tid]);
}

__global__ __launch_bounds__(256) void pack_lnkv(
    const float* __restrict__ g, const float* __restrict__ bb,
    float* __restrict__ dst) {
  int t = blockIdx.x * 256 + threadIdx.x;
  if (t < 2 * D) dst[t] = g[t];
  else if (t < 4 * D) dst[t] = bb[t - 2 * D];
}

// ---------------------------------------------------------------------------
__global__ __launch_bounds__(256) void transpose_all(
    const float* __restrict__ Wq_, const float* __restrict__ Wk_,
    const float* __restrict__ Wv_, const float* __restrict__ Wo_,
    const float* __restrict__ W1_, const float* __restrict__ W2_,
    u16* __restrict__ WT) {
  const long DD = (long)D * D, DFF = (long)D * FF;
  const long LSTR = 4 * DD + 2 * DFF;
  long t = (long)blockIdx.x * 256 + threadIdx.x;
  if (t >= NL * LSTR) return;
  int l = (int)(t / LSTR);
  long r = t - (long)l * LSTR;
  const float* src;
  long dstbase, e;
  int K_, N_;
  if (r < 4 * DD) {
    int which = (int)(r >> 16);
    e = r & (DD - 1);
    K_ = D; N_ = D;
    src = (which == 0 ? Wk_ : which == 1 ? Wv_ : which == 2 ? Wq_ : Wo_) +
          (long)l * DD;
    dstbase = l * LSTR + which * DD;
  } else if (r < 4 * DD + DFF) {
    e = r - 4 * DD;
    K_ = D; N_ = FF;
    src = W1_ + (long)l * DFF;
    dstbase = l * LSTR + 4 * DD;
  } else {
    e = r - 4 * DD - DFF;
    K_ = FF; N_ = D;
    src = W2_ + (long)l * DFF;
    dstbase = l * LSTR + 4 * DD + DFF;
  }
  int k = (int)(e / N_), n = (int)(e % N_);
  WT[dstbase + (long)n * K_ + k] = f2bs(src[e]);
}

// ---------------------------------------------------------------------------
// bf16 MFMA GEMM (64x64 tile, BK=32, 4 waves).
// EPI 0: bias->bf16; 1: gelu->bf16; 2: resid+mask->f32
// ---------------------------------------------------------------------------
template <int EPI>
__global__ __launch_bounds__(256) void gemm_mfma(
    const u16* __restrict__ A, const u16* __restrict__ BT,
    const float* __restrict__ bias, void* __restrict__ Cv,
    const float* __restrict__ resid, const int* __restrict__ mask, int M,
    int N, int K) {
  __shared__ short As[64][40];
  __shared__ short Bs[64][40];
  int bm = blockIdx.y * 64, bn = blockIdx.x * 64;
  int tid = threadIdx.x;
  int lane = tid & 63, w = tid >> 6;
  int g = lane >> 4, li = lane & 15;
  int wr = w >> 1, wc = w & 1;
  f32x4 acc[2][2] = {};

  int srow = tid >> 2, skc = (tid & 3) * 8;
  for (int k0 = 0; k0 < K; k0 += 32) {
    {
      int grow = bm + srow;
      bf16x8 av = {};
      if (grow < M)
        av = *reinterpret_cast<const bf16x8*>(A + (long)grow * K + k0 + skc);
      *reinterpret_cast<bf16x8*>(&As[srow][skc]) = av;
      bf16x8 bv = *reinterpret_cast<const bf16x8*>(
          BT + (long)(bn + srow) * K + k0 + skc);
      *reinterpret_cast<bf16x8*>(&Bs[srow][skc]) = bv;
    }
    __syncthreads();
    bf16x8 a0 = *reinterpret_cast<const bf16x8*>(&As[wr * 32 + li][g * 8]);
    bf16x8 a1 = *reinterpret_cast<const bf16x8*>(&As[wr * 32 + 16 + li][g * 8]);
    bf16x8 b0 = *reinterpret_cast<const bf16x8*>(&Bs[wc * 32 + li][g * 8]);
    bf16x8 b1 = *reinterpret_cast<const bf16x8*>(&Bs[wc * 32 + 16 + li][g * 8]);
    acc[0][0] = __builtin_amdgcn_mfma_f32_16x16x32_bf16(a0, b0, acc[0][0], 0, 0, 0);
    acc[0][1] = __builtin_amdgcn_mfma_f32_16x16x32_bf16(a0, b1, acc[0][1], 0, 0, 0);
    acc[1][0] = __builtin_amdgcn_mfma_f32_16x16x32_bf16(a1, b0, acc[1][0], 0, 0, 0);
    acc[1][1] = __builtin_amdgcn_mfma_f32_16x16x32_bf16(a1, b1, acc[1][1], 0, 0, 0);
    __syncthreads();
  }

#pragma unroll
  for (int mr = 0; mr < 2; ++mr)
#pragma unroll
    for (int nr = 0; nr < 2; ++nr)
#pragma unroll
      for (int r = 0; r < 4; ++r) {
        int row = bm + wr * 32 + mr * 16 + g * 4 + r;
        int col = bn + wc * 32 + nr * 16 + li;
        if (row >= M) continue;
        float v = acc[mr][nr][r] + bias[col];
        if (EPI == 1) v = gelu_exact(v);
        if (EPI == 2) {
          v += resid[(long)row * N + col];
          v = mask[row] ? v : 0.f;
          ((float*)Cv)[(long)row * N + col] = v;
        } else {
          ((u16*)Cv)[(long)row * N + col] = f2bs(v);
        }
      }
}

// ---------------------------------------------------------------------------
// Fused K+V projection GEMM: A = kv_ln [8192x256], BT = [WkT; WvT] (512x256).
// bn < 256 -> Kh[b][h][key][d]; bn >= 256 -> Vh[b][h][key/32][d][key%32].
// ---------------------------------------------------------------------------
__global__ __launch_bounds__(256) void gemm_kv(
    const u16* __restrict__ A, const u16* __restrict__ BT,
    const float* __restrict__ biasK, const float* __restrict__ biasV,
    u16* __restrict__ Kh, u16* __restrict__ Vh) {
  __shared__ short As[64][40];
  __shared__ short Bs[64][40];
  int bm = blockIdx.y * 64, bn = blockIdx.x * 64;
  int tid = threadIdx.x;
  int lane = tid & 63, w = tid >> 6;
  int g = lane >> 4, li = lane & 15;
  int wr = w >> 1, wc = w & 1;
  f32x4 acc[2][2] = {};

  int srow = tid >> 2, skc = (tid & 3) * 8;
  for (int k0 = 0; k0 < D; k0 += 32) {
    {
      bf16x8 av = *reinterpret_cast<const bf16x8*>(
          A + (long)(bm + srow) * D + k0 + skc);
      *reinterpret_cast<bf16x8*>(&As[srow][skc]) = av;
      bf16x8 bv = *reinterpret_cast<const bf16x8*>(
          BT + (long)(bn + srow) * D + k0 + skc);
      *reinterpret_cast<bf16x8*>(&Bs[srow][skc]) = bv;
    }
    __syncthreads();
    bf16x8 a0 = *reinterpret_cast<const bf16x8*>(&As[wr * 32 + li][g * 8]);
    bf16x8 a1 = *reinterpret_cast<const bf16x8*>(&As[wr * 32 + 16 + li][g * 8]);
    bf16x8 b0 = *reinterpret_cast<const bf16x8*>(&Bs[wc * 32 + li][g * 8]);
    bf16x8 b1 = *reinterpret_cast<const bf16x8*>(&Bs[wc * 32 + 16 + li][g * 8]);
    acc[0][0] = __builtin_amdgcn_mfma_f32_16x16x32_bf16(a0, b0, acc[0][0], 0, 0, 0);
    acc[0][1] = __builtin_amdgcn_mfma_f32_16x16x32_bf16(a0, b1, acc[0][1], 0, 0, 0);
    acc[1][0] = __builtin_amdgcn_mfma_f32_16x16x32_bf16(a1, b0, acc[1][0], 0, 0, 0);
    acc[1][1] = __builtin_amdgcn_mfma_f32_16x16x32_bf16(a1, b1, acc[1][1], 0, 0, 0);
    __syncthreads();
  }

  if (bn < 256) {
    // K epilogue: Kh[b][h][key][d] (64B contiguous key rows)
    __shared__ u16 Ct[64][72];
#pragma unroll
    for (int mr = 0; mr < 2; ++mr)
#pragma unroll
      for (int nr = 0; nr < 2; ++nr)
#pragma unroll
        for (int r = 0; r < 4; ++r) {
          int rowL = wr * 32 + mr * 16 + g * 4 + r;
          int colL = wc * 32 + nr * 16 + li;
          Ct[rowL][colL] = f2bs(acc[mr][nr][r] + biasK[bn + colL]);
        }
    __syncthreads();
#pragma unroll
    for (int p = 0; p < 2; ++p) {
      int rowL = (tid >> 3) + p * 32;
      int c8 = (tid & 7) * 8;
      int grow = bm + rowL;
      int b2 = grow >> 12, key = grow & (L - 1);
      int gcol = bn + c8;
      int hh = gcol >> 5, dd = gcol & (HD - 1);
      u16* dst = Kh + (((long)(b2 * H + hh) * L + key) * 32 + dd);
      *reinterpret_cast<bf16x8*>(dst) =
          *reinterpret_cast<const bf16x8*>(&Ct[rowL][c8]);
    }
  } else {
    // V epilogue: Vh[b][h][key/32][d][key%32]
    int vbn = bn - 256;
    __shared__ u16 Ct[64][72];
#pragma unroll
    for (int mr = 0; mr < 2; ++mr)
#pragma unroll
      for (int nr = 0; nr < 2; ++nr)
#pragma unroll
        for (int r = 0; r < 4; ++r) {
          int rowL = wr * 32 + mr * 16 + g * 4 + r;
          int colL = wc * 32 + nr * 16 + li;
          Ct[colL][rowL] = f2bs(acc[mr][nr][r] + biasV[vbn + colL]);
        }
    __syncthreads();
    int b2 = bm >> 12;
#pragma unroll
    for (int p = 0; p < 2; ++p) {
      int colL = (tid >> 3) + p * 32;
      int rem = tid & 7;
      int kb = rem >> 2, k8 = (rem & 3) * 8;
      int gcol = vbn + colL;
      int hh = gcol >> 5, dd = gcol & (HD - 1);
      int kb32 = ((bm & (L - 1)) >> 5) + kb;
      u16* dst = Vh +
                 (((long)(b2 * H + hh) * (L / 32) + kb32) * 1024 + dd * 32 + k8);
      *reinterpret_cast<bf16x8*>(dst) =
          *reinterpret_cast<const bf16x8*>(&Ct[colL][kb * 32 + k8]);
    }
  }
}

// ---------------------------------------------------------------------------
// Fused flash attention: 256 threads = 4 split-K waves per (b,h,32-q tile).
// Wave-private LDS double-buffer filled by global_load_lds DMA (no barriers
// in the loop, counted vmcnt). No-max softmax (scores are O(1); softmax is
// shift-invariant, fp32 exp2 cannot overflow here), so split-K combine is a
// plain sum. XCD-aware block swizzle.
// ---------------------------------------------------------------------------
__global__ __launch_bounds__(256) void attn_mfma(
    const u16* __restrict__ Qb, const u16* __restrict__ Kh,
    const u16* __restrict__ Vh, u16* __restrict__ AO) {
  __shared__ alignas(16) char pool[NSPLIT * 8192];  // 32 KB
  int i = blockIdx.x;
  int xcd = i & 7, slot = i >> 3;          // 66 slots per XCD
  int bh = (xcd << 1) | (slot >= NQT ? 1 : 0);
  int qt = (slot >= NQT) ? slot - NQT : slot;
  int h = bh & 7;
  int b = bh >> 3;
  int tid = threadIdx.x, w = tid >> 6, lane = tid & 63;
  int g = lane >> 4, li = lane & 15;

  fr qf0, qf1;
  {
    const float QSC = 0.25509836048f;  // (1/sqrt(32)) * log2(e)
#pragma unroll
    for (int qb = 0; qb < 2; ++qb) {
      int qrow = qt * 32 + qb * 16 + li;
      if (qrow >= Q_MAX) qrow = Q_MAX - 1;
      bf16x8 raw = *reinterpret_cast<const bf16x8*>(
          Qb + ((long)(b * Q_MAX + qrow)) * D + h * HD + g * 8);
      fr& qf = qb ? qf1 : qf0;
#pragma unroll
      for (int j = 0; j < 4; ++j)
        qf.i[j] = (int)cvt_pk(bs2f((u16)raw[2 * j]) * QSC,
                              bs2f((u16)raw[2 * j + 1]) * QSC);
    }
  }

  f32x4 acc00 = {}, acc01 = {}, acc10 = {}, acc11 = {};
  float den0 = 0.f, den1 = 0.f;
  const f32x4 z = {};

  const u16* kbase = Kh + ((long)(b * H + h) * L) * HD;
  const u16* vbase = Vh + ((long)(b * H + h) * L) * HD;
  int kstart = w * KCHUNK;
  char* wbase = pool + w * 8192;  // wave-private: 2 bufs x (2KB K + 2KB V)

  // prologue: stage tile 0 into buf 0
  {
    const u16* ks = kbase + (long)kstart * HD + lane * 8;
    const u16* vs = vbase + (long)kstart * HD + lane * 8;
    u16* lk = (u16*)wbase;
    GLL16(ks, lk);
    GLL16(ks + 512, lk + 512);
    GLL16(vs, lk + 1024);
    GLL16(vs + 512, lk + 1536);
  }

  for (int t = 0; t < NT; ++t) {
    char* cbuf = wbase + (t & 1) * 4096;
    if (t + 1 < NT) {
      char* nbuf = wbase + ((t + 1) & 1) * 4096;
      const u16* ks = kbase + (long)(kstart + (t + 1) * 32) * HD + lane * 8;
      const u16* vs = vbase + (long)(kstart + (t + 1) * 32) * HD + lane * 8;
      u16* lk = (u16*)nbuf;
      GLL16(ks, lk);
      GLL16(ks + 512, lk + 512);
      GLL16(vs, lk + 1024);
      GLL16(vs + 512, lk + 1536);
      asm volatile("s_waitcnt vmcnt(4)" ::: "memory");
    } else {
      asm volatile("s_waitcnt vmcnt(0)" ::: "memory");
    }
    __builtin_amdgcn_sched_barrier(0);

    const u16* kl = (const u16*)cbuf;
    const u16* vl = kl + 1024;
    bf16x8 kf0 = *reinterpret_cast<const bf16x8*>(kl + li * 32 + g * 8);
    bf16x8 kf1 = *reinterpret_cast<const bf16x8*>(kl + (16 + li) * 32 + g * 8);
    uint2 va0 = *reinterpret_cast<const uint2*>(vl + li * 32 + 4 * g);
    uint2 vb0 = *reinterpret_cast<const uint2*>(vl + li * 32 + 16 + 4 * g);
    uint2 va1 = *reinterpret_cast<const uint2*>(vl + (16 + li) * 32 + 4 * g);
    uint2 vb1 = *reinterpret_cast<const uint2*>(vl + (16 + li) * 32 + 16 + 4 * g);

    f32x4 s00 = __builtin_amdgcn_mfma_f32_16x16x32_bf16(kf0, qf0.h, z, 0, 0, 0);
    f32x4 s10 = __builtin_amdgcn_mfma_f32_16x16x32_bf16(kf1, qf0.h, z, 0, 0, 0);
    f32x4 s01 = __builtin_amdgcn_mfma_f32_16x16x32_bf16(kf0, qf1.h, z, 0, 0, 0);
    f32x4 s11 = __builtin_amdgcn_mfma_f32_16x16x32_bf16(kf1, qf1.h, z, 0, 0, 0);

    float p00[4], p10[4], p01[4], p11[4];
#pragma unroll
    for (int r = 0; r < 4; ++r) {
      p00[r] = exp2f(s00[r]);
      p10[r] = exp2f(s10[r]);
      p01[r] = exp2f(s01[r]);
      p11[r] = exp2f(s11[r]);
      den0 += p00[r] + p10[r];
      den1 += p01[r] + p11[r];
    }
    fr pf0, pf1;
    pf0.i[0] = (int)cvt_pk(p00[0], p00[1]);
    pf0.i[1] = (int)cvt_pk(p00[2], p00[3]);
    pf0.i[2] = (int)cvt_pk(p10[0], p10[1]);
    pf0.i[3] = (int)cvt_pk(p10[2], p10[3]);
    pf1.i[0] = (int)cvt_pk(p01[0], p01[1]);
    pf1.i[1] = (int)cvt_pk(p01[2], p01[3]);
    pf1.i[2] = (int)cvt_pk(p11[0], p11[1]);
    pf1.i[3] = (int)cvt_pk(p11[2], p11[3]);

    fr v0, v1;
    v0.i = (i32x4){(int)va0.x, (int)va0.y, (int)vb0.x, (int)vb0.y};
    v1.i = (i32x4){(int)va1.x, (int)va1.y, (int)vb1.x, (int)vb1.y};
    acc00 = __builtin_amdgcn_mfma_f32_16x16x32_bf16(v0.h, pf0.h, acc00, 0, 0, 0);
    acc01 = __builtin_amdgcn_mfma_f32_16x16x32_bf16(v0.h, pf1.h, acc01, 0, 0, 0);
    acc10 = __builtin_amdgcn_mfma_f32_16x16x32_bf16(v1.h, pf0.h, acc10, 0, 0, 0);
    acc11 = __builtin_amdgcn_mfma_f32_16x16x32_bf16(v1.h, pf1.h, acc11, 0, 0, 0);
  }

  // reduce per-lane denominators over g
  den0 += __shfl_xor(den0, 16, 64);
  den0 += __shfl_xor(den0, 32, 64);
  den1 += __shfl_xor(den1, 16, 64);
  den1 += __shfl_xor(den1, 32, 64);

  // combine: overlay staging LDS (all waves done with it after barrier)
  __syncthreads();
  float (*accs)[32][33] = (float(*)[32][33])pool;
  float (*dsh)[32] = (float(*)[32])(pool + NSPLIT * 32 * 33 * 4);
#pragma unroll
  for (int r = 0; r < 4; ++r) {
    accs[w][g * 4 + r][li] = acc00[r];
    accs[w][g * 4 + r][16 + li] = acc01[r];
    accs[w][16 + g * 4 + r][li] = acc10[r];
    accs[w][16 + g * 4 + r][16 + li] = acc11[r];
  }
  if (g == 0) {
    dsh[w][li] = den0;
    dsh[w][16 + li] = den1;
  }
  __syncthreads();

  int q = tid >> 3, d4 = (tid & 7) * 4;
  float Den = dsh[0][q] + dsh[1][q] + dsh[2][q] + dsh[3][q];
  float inv = 1.f / Den;
  float o[4];
#pragma unroll
  for (int j = 0; j < 4; ++j)
    o[j] = accs[0][d4 + j][q] + accs[1][d4 + j][q] + accs[2][d4 + j][q] +
           accs[3][d4 + j][q];
  int qrow = qt * 32 + q;
  if (qrow < Q_MAX) {
    uint2 pk = {cvt_pk(o[0] * inv, o[1] * inv), cvt_pk(o[2] * inv, o[3] * inv)};
    *reinterpret_cast<uint2*>(
        AO + ((long)(b * Q_MAX + qrow)) * D + h * HD + d4) = pk;
  }
}

// ---------------------------------------------------------------------------
__global__ __launch_bounds__(256) void head_kernel(
    const float* __restrict__ enc, const float* __restrict__ hW,
    const float* __restrict__ hb, float* __restrict__ out) {
  int row = blockIdx.x * 4 + (threadIdx.x >> 6);
  int lane = threadIdx.x & 63;
  const float4 a = *reinterpret_cast<const float4*>(enc + (long)row * D + lane * 4);
  float c0 = 0.f, c1 = 0.f, c2 = 0.f;
  const float av[4] = {a.x, a.y, a.z, a.w};
#pragma unroll
  for (int i = 0; i < 4; ++i) {
    int k = lane * 4 + i;
    c0 += av[i] * hW[k * 3];
    c1 += av[i] * hW[k * 3 + 1];
    c2 += av[i] * hW[k * 3 + 2];
  }
#pragma unroll
  for (int off = 32; off; off >>= 1) {
    c0 += __shfl_down(c0, off, 64);
    c1 += __shfl_down(c1, off, 64);
    c2 += __shfl_down(c2, off, 64);
  }
  if (lane == 0) {
    out[(long)row * 3] = c0 + hb[0];
    out[(long)row * 3 + 1] = c1 + hb[1];
    out[(long)row * 3 + 2] = c2 + hb[2];
  }
}

// ---------------------------------------------------------------------------
__global__ __launch_bounds__(64) void overwrite_kernel(
    const float* __restrict__ q_stream, const int* __restrict__ idx,
    const int* __restrict__ mask, const float* __restrict__ hW,
    const float* __restrict__ hb, float* __restrict__ out) {
  int j = blockIdx.x;
  if (!mask[j]) return;
  int b = j / Q_MAX;
  int p = idx[j];
  int lane = threadIdx.x;
  const float* a = q_stream + (long)j * D;
  float a0 = a[lane], a1 = a[lane + 64], a2 = a[lane + 128],
        a3 = a[lane + 192];
  for (int c = 0; c < 3; ++c) {
    float s = a0 * hW[lane * 3 + c] + a1 * hW[(lane + 64) * 3 + c] +
              a2 * hW[(lane + 128) * 3 + c] + a3 * hW[(lane + 192) * 3 + c];
    for (int off = 32; off > 0; off >>= 1) s += __shfl_down(s, off, 64);
    if (lane == 0) out[((long)b * L + p) * 3 + c] = s + hb[c];
  }
}

// ---------------------------------------------------------------------------
extern "C" void kernel_launch(void* const* d_in, const int* in_sizes, int n_in,
                              void* d_out, int out_size, void* d_ws,
                              size_t ws_size, hipStream_t stream) {
  const float* enc = (const float*)d_in[0];
  const float* clog = (const float*)d_in[1];
  const float* ln_q_g = (const float*)d_in[2];
  const float* ln_q_b = (const float*)d_in[3];
  const float* ln_kv_g = (const float*)d_in[4];
  const float* ln_kv_b = (const float*)d_in[5];
  const float* Wq = (const float*)d_in[6];
  const float* bq = (const float*)d_in[7];
  const float* Wk = (const float*)d_in[8];
  const float* bk = (const float*)d_in[9];
  const float* Wv = (const float*)d_in[10];
  const float* bv = (const float*)d_in[11];
  const float* Wo = (const float*)d_in[12];
  const float* bo = (const float*)d_in[13];
  const float* ffn_g = (const float*)d_in[14];
  const float* ffn_b = (const float*)d_in[15];
  const float* W1 = (const float*)d_in[16];
  const float* b1 = (const float*)d_in[17];
  const float* W2 = (const float*)d_in[18];
  const float* b2 = (const float*)d_in[19];
  const float* head_W = (const float*)d_in[20];
  const float* head_b = (const float*)d_in[21];
  float* out = (float*)d_out;

  char* ws = (char*)d_ws;
  float* q_stream = (float*)ws;            ws += (long)QROWS * D * 4;
  u16* kvl0 = (u16*)ws;                    ws += (long)KVROWS * D * 2;
  u16* kvl1 = (u16*)ws;                    ws += (long)KVROWS * D * 2;
  u16* Khbuf = (u16*)ws;                   ws += (long)B * H * L * HD * 2;
  u16* Vhbuf = (u16*)ws;                   ws += (long)B * H * L * HD * 2;
  u16* q_ln = (u16*)ws;                    ws += (long)QROWS * D * 2;
  u16* Qbuf = (u16*)ws;                    ws += (long)QROWS * D * 2;
  u16* AObuf = (u16*)ws;                   ws += (long)QROWS * D * 2;
  u16* H1buf = (u16*)ws;                   ws += (long)QROWS * FF * 2;
  u16* WT = (u16*)ws;                      ws += (long)NL * (4 * D * D + 2 * D * FF) * 2;
  float* lnkv_pack = (float*)ws;           ws += 4 * D * 4;
  int* idxbuf = (int*)ws;                  ws += QROWS * 4;
  int* maskbuf = (int*)ws;

  const long DD = (long)D * D, DFF = (long)D * FF;
  const long LSTR = 4 * DD + 2 * DFF;

  transpose_all<<<(int)((NL * LSTR + 255) / 256), 256, 0, stream>>>(
      Wq, Wk, Wv, Wo, W1, W2, WT);
  pack_lnkv<<<(4 * D + 255) / 256, 256, 0, stream>>>(ln_kv_g, ln_kv_b, lnkv_pack);
  ln_kv2<<<KVROWS, 256, 0, stream>>>(enc, kvl0, kvl1, lnkv_pack);
  select_kernel<<<B, 1024, 0, stream>>>(clog, idxbuf, maskbuf);
  gather_kernel<<<QROWS, 256, 0, stream>>>(enc, idxbuf, q_stream);

  for (int l = 0; l < NL; ++l) {
    u16* base = WT + l * LSTR;
    u16* kv_ln = (l == 0) ? kvl0 : kvl1;

    ln_bf16<<<QROWS, 256, 0, stream>>>(q_stream, q_ln, ln_q_g + l * D, ln_q_b + l * D);

    dim3 gKV(512 / 64, KVROWS / 64);
    gemm_kv<<<gKV, 256, 0, stream>>>(kv_ln, base, bk + l * D, bv + l * D,
                                     Khbuf, Vhbuf);
    dim3 gQ(D / 64, (QROWS + 63) / 64);
    gemm_mfma<0><<<gQ, 256, 0, stream>>>(q_ln, base + 2 * DD, bq + l * D,
                                         (void*)Qbuf, nullptr, nullptr,
                                         QROWS, D, D);

    attn_mfma<<<B * H * NQT, 256, 0, stream>>>(Qbuf, Khbuf, Vhbuf, AObuf);

    gemm_mfma<2><<<gQ, 256, 0, stream>>>(AObuf, base + 3 * DD, bo + l * D,
                                         (void*)q_stream, q_stream, maskbuf,
                                         QROWS, D, D);

    ln_bf16<<<QROWS, 256, 0, stream>>>(q_stream, q_ln, ffn_g + l * D, ffn_b + l * D);
    dim3 gF1(FF / 64, (QROWS + 63) / 64);
    gemm_mfma<1><<<gF1, 256, 0, stream>>>(q_ln, base + 4 * DD, b1 + l * FF,
                                          (void*)H1buf, nullptr, nullptr,
                                          QROWS, FF, D);
    dim3 gF2(D / 64, (QROWS + 63) / 64);
    gemm_mfma<2><<<gF2, 256, 0, stream>>>(H1buf, base + 4 * DD + DFF,
                                          b2 + l * D, (void*)q_stream,
                                          q_stream, maskbuf, QROWS, D, FF);
  }

  head_kernel<<<KVROWS / 4, 256, 0, stream>>>(enc, head_W, head_b, out);
  overwrite_kernel<<<QROWS, 64, 0, stream>>>(q_stream, idxbuf, maskbuf, head_W,
                                             head_b, out);
}